// Round 1
// baseline (393.426 us; speedup 1.0000x reference)
//
#include <hip/hip_runtime.h>
#include <stdint.h>

#define NB 4
#define NS 2048
#define ND 1024
#define NH 16
#define NM 8192   // NB*NS

typedef __attribute__((ext_vector_type(4))) float          f32x4;
typedef __attribute__((ext_vector_type(8))) __bf16         bf16x8;
typedef __attribute__((ext_vector_type(8))) unsigned short u16x8;
typedef __attribute__((ext_vector_type(4))) unsigned short u16x4;

static __device__ __forceinline__ unsigned short f2bf(float f) {
  unsigned u = __builtin_bit_cast(unsigned, f);
  return (unsigned short)((u + 0x7fffu + ((u >> 16) & 1u)) >> 16);
}

static __device__ __forceinline__ void gld_lds16(const void* g, void* l) {
  __builtin_amdgcn_global_load_lds((const __attribute__((address_space(1))) void*)g,
                                   (__attribute__((address_space(3))) void*)l, 16, 0, 0);
}

// ---------------------------------------------------------------- cast f32->bf16
__global__ __launch_bounds__(256) void cast_bf16(const float* __restrict__ in,
                                                 unsigned short* __restrict__ out,
                                                 int n4) {
  int i = blockIdx.x * 256 + threadIdx.x;
  if (i >= n4) return;
  f32x4 v = ((const f32x4*)in)[i];
  u16x4 o;
#pragma unroll
  for (int e = 0; e < 4; ++e) o[e] = f2bf(v[e]);
  ((u16x4*)out)[i] = o;
}

// ---------------------------------------------------------------- 128x128 NT GEMM
// C[m,n] = sum_k A[m,k]*Bw[n,k]; A,Bw bf16 K-major, K=ND=1024.
// MODE: OUTF32 -> f32 C; else bf16 C with optional fused interleaved RoPE.
template<bool OUTF32>
static __device__ __forceinline__ void gemm_body(
    const unsigned short* __restrict__ A,
    const unsigned short* __restrict__ Bw,
    const int* __restrict__ tp,
    void* __restrict__ Cout,
    bool rope)
{
  __shared__ unsigned short As[128 * 32];
  __shared__ unsigned short Bs[128 * 32];

  const int tid  = threadIdx.x;
  const int wid  = tid >> 6, lane = tid & 63;
  const int ln   = lane & 15, kg = lane >> 4;
  const int wr   = wid >> 1,  wc = wid & 1;
  const int m0   = blockIdx.y * 128, n0 = blockIdx.x * 128;

  // staging chunks: chunk c -> row=c>>2, slot=c&3 (8 elems each); source k-block
  // XOR-swizzled so the linear global_load_lds dest yields conflict-light reads.
  const int c0 = tid, c1 = tid + 256;
  const int r0 = c0 >> 2, s0 = c0 & 3;
  const int r1 = c1 >> 2, s1 = c1 & 3;
  const int f0 = (r0 & 3) ^ ((r0 >> 2) & 3);
  const int f1 = (r1 & 3) ^ ((r1 >> 2) & 3);

  const unsigned short* gA0 = A  + (size_t)(m0 + r0) * ND + ((s0 ^ f0) * 8);
  const unsigned short* gA1 = A  + (size_t)(m0 + r1) * ND + ((s1 ^ f1) * 8);
  const unsigned short* gB0 = Bw + (size_t)(n0 + r0) * ND + ((s0 ^ f0) * 8);
  const unsigned short* gB1 = Bw + (size_t)(n0 + r1) * ND + ((s1 ^ f1) * 8);

  unsigned short* lA0 = &As[(wid * 64) * 8];
  unsigned short* lA1 = &As[(256 + wid * 64) * 8];
  unsigned short* lB0 = &Bs[(wid * 64) * 8];
  unsigned short* lB1 = &Bs[(256 + wid * 64) * 8];

  const int fql = (ln & 3) ^ ((ln >> 2) & 3);
  int offA[4], offB[4];
#pragma unroll
  for (int i = 0; i < 4; ++i) {
    offA[i] = (wr * 64 + i * 16 + ln) * 32 + ((kg ^ fql) * 8);
    offB[i] = (wc * 64 + i * 16 + ln) * 32 + ((kg ^ fql) * 8);
  }

  f32x4 acc[4][4];
#pragma unroll
  for (int i = 0; i < 4; ++i)
#pragma unroll
    for (int j = 0; j < 4; ++j) acc[i][j] = (f32x4){0.f, 0.f, 0.f, 0.f};

  for (int kt = 0; kt < 32; ++kt) {
    gld_lds16(gA0, lA0);
    gld_lds16(gA1, lA1);
    gld_lds16(gB0, lB0);
    gld_lds16(gB1, lB1);
    gA0 += 32; gA1 += 32; gB0 += 32; gB1 += 32;
    __syncthreads();
    bf16x8 af[4], bfr[4];
#pragma unroll
    for (int i = 0; i < 4; ++i) af[i] = *(const bf16x8*)&As[offA[i]];
#pragma unroll
    for (int j = 0; j < 4; ++j) bfr[j] = *(const bf16x8*)&Bs[offB[j]];
#pragma unroll
    for (int i = 0; i < 4; ++i)
#pragma unroll
      for (int j = 0; j < 4; ++j)
        acc[i][j] = __builtin_amdgcn_mfma_f32_16x16x32_bf16(af[i], bfr[j], acc[i][j], 0, 0, 0);
    __syncthreads();
  }

  if (OUTF32) {
    float* C = (float*)Cout;
#pragma unroll
    for (int i = 0; i < 4; ++i)
#pragma unroll
      for (int j = 0; j < 4; ++j)
#pragma unroll
        for (int r = 0; r < 4; ++r) {
          int m = m0 + wr * 64 + i * 16 + kg * 4 + r;
          int n = n0 + wc * 64 + j * 16 + ln;
          C[(size_t)m * ND + n] = acc[i][j][r];
        }
  } else {
    unsigned short* C = (unsigned short*)Cout;
#pragma unroll
    for (int i = 0; i < 4; ++i)
#pragma unroll
      for (int r = 0; r < 4; ++r) {
        int m = m0 + wr * 64 + i * 16 + kg * 4 + r;
        float pos = rope ? (float)tp[m] : 0.f;
#pragma unroll
        for (int j = 0; j < 4; ++j) {
          int n = n0 + wc * 64 + j * 16 + ln;
          float v  = acc[i][j][r];
          float pv = __shfl_xor(v, 1);   // pair partner (adjacent column)
          float outv = v;
          if (rope) {
            int   ip   = (n & 63) >> 1;            // freq index within head
            float invf = __expf(-0.28782313662425572f * (float)ip); // theta^(-ip/32)
            float ang  = pos * invf;
            float sn, cs;
            __sincosf(ang, &sn, &cs);
            outv = (n & 1) ? (pv * sn + v * cs) : (v * cs - pv * sn);
          }
          C[(size_t)m * ND + n] = f2bf(outv);
        }
      }
  }
}

__global__ __launch_bounds__(256) void gemm_qkv(
    const unsigned short* __restrict__ xb,
    const unsigned short* __restrict__ Wqb,
    const unsigned short* __restrict__ Wkb,
    const unsigned short* __restrict__ Wvb,
    const int* __restrict__ tp,
    unsigned short* __restrict__ Qt,
    unsigned short* __restrict__ Kt,
    unsigned short* __restrict__ Vt)
{
  int z = blockIdx.z;
  const unsigned short* Bw = (z == 0) ? Wqb : (z == 1) ? Wkb : Wvb;
  unsigned short* C        = (z == 0) ? Qt  : (z == 1) ? Kt  : Vt;
  gemm_body<false>(xb, Bw, tp, C, z < 2);
}

__global__ __launch_bounds__(256) void gemm_out(
    const unsigned short* __restrict__ Ot,
    const unsigned short* __restrict__ Wob,
    float* __restrict__ C)
{
  gemm_body<true>(Ot, Wob, nullptr, C, false);
}

// ---------------------------------------------------------------- flash attention
// grid (32 qblocks, 64 bh). 256 thr = 4 waves x 16 q-rows. KV tiles of 64.
// Q,K,V,O are [B,S,H*64] bf16. Causal, scale 1/8.
__global__ __launch_bounds__(256) void attn_kernel(
    const unsigned short* __restrict__ Q,
    const unsigned short* __restrict__ K,
    const unsigned short* __restrict__ V,
    unsigned short* __restrict__ O)
{
  __shared__ unsigned short Ks[64 * 64];
  __shared__ unsigned short Vs[64 * 64];   // transposed: [d][kv] with slot swizzle
  __shared__ unsigned short Ps[4][16 * 64];

  const int tid = threadIdx.x;
  const int wid = tid >> 6, lane = tid & 63;
  const int ln  = lane & 15, kg = lane >> 4;
  const int qb  = blockIdx.x;
  const int bh  = blockIdx.y;
  const int b   = bh >> 4, h = bh & 15;

  const size_t base = (size_t)b * NS * ND + (size_t)h * 64;
  const int q0 = qb * 64 + wid * 16;

  bf16x8 qf[2];
  {
    const unsigned short* qp = Q + base + (size_t)(q0 + ln) * ND + kg * 8;
    qf[0] = *(const bf16x8*)qp;
    qf[1] = *(const bf16x8*)(qp + 32);
  }

  float m_run[4], l_run[4], alpha[4];
  f32x4 acc_o[4];
#pragma unroll
  for (int r = 0; r < 4; ++r) { m_run[r] = -1e30f; l_run[r] = 0.f; }
#pragma unroll
  for (int dj = 0; dj < 4; ++dj) acc_o[dj] = (f32x4){0.f, 0.f, 0.f, 0.f};

  // staging chunk coords (2 chunks/thread per tensor): kv=c>>3, slot=c&7
  const int cA = tid,       cB = tid + 256;
  const int kvA = cA >> 3,  slA = cA & 7;
  const int kvB = cB >> 3,  slB = cB & 7;

  unsigned short* lK0 = &Ks[(wid * 64) * 8];
  unsigned short* lK1 = &Ks[(256 + wid * 64) * 8];

  const unsigned short* Kg0 = K + base + (size_t)kvA * ND + ((slA ^ (kvA & 7)) * 8);
  const unsigned short* Kg1 = K + base + (size_t)kvB * ND + ((slB ^ (kvB & 7)) * 8);
  const unsigned short* Vg0 = V + base + (size_t)kvA * ND + slA * 8;
  const unsigned short* Vg1 = V + base + (size_t)kvB * ND + slB * 8;

  unsigned short* myP = &Ps[wid][0];
  const int fql = (ln >> 2) & 3;

  for (int kvb = 0; kvb <= qb; ++kvb) {
    const size_t koff = (size_t)(kvb * 64) * ND;
    // K: async global->LDS, source-swizzled (linear dest)
    gld_lds16(Kg0 + koff, lK0);
    gld_lds16(Kg1 + koff, lK1);
    // V: reg-staged transpose into Vs[d][kv] with slot swizzle
    {
      u16x8 v0 = *(const u16x8*)(Vg0 + koff);
      u16x8 v1 = *(const u16x8*)(Vg1 + koff);
#pragma unroll
      for (int e = 0; e < 8; ++e) {
        int d  = slA * 8 + e;
        int sl = (kvA >> 3) ^ (d & 7) ^ ((d >> 3) & 7);
        Vs[d * 64 + sl * 8 + (kvA & 7)] = v0[e];
      }
#pragma unroll
      for (int e = 0; e < 8; ++e) {
        int d  = slB * 8 + e;
        int sl = (kvB >> 3) ^ (d & 7) ^ ((d >> 3) & 7);
        Vs[d * 64 + sl * 8 + (kvB & 7)] = v1[e];
      }
    }
    __syncthreads();

    // S = Q K^T : 4 col-tiles of 16; each lane ends with S[q=kg*4+r][kv=j*16+ln]
    f32x4 sf[4];
#pragma unroll
    for (int j = 0; j < 4; ++j) {
      int kvr = j * 16 + ln;
      bf16x8 k0 = *(const bf16x8*)&Ks[kvr * 64 + ((kg ^ (kvr & 7)) * 8)];
      bf16x8 k1 = *(const bf16x8*)&Ks[kvr * 64 + (((4 + kg) ^ (kvr & 7)) * 8)];
      f32x4 z = (f32x4){0.f, 0.f, 0.f, 0.f};
      z = __builtin_amdgcn_mfma_f32_16x16x32_bf16(qf[0], k0, z, 0, 0, 0);
      z = __builtin_amdgcn_mfma_f32_16x16x32_bf16(qf[1], k1, z, 0, 0, 0);
      sf[j] = z;
    }

    const bool diag = (kvb == qb);
#pragma unroll
    for (int j = 0; j < 4; ++j)
#pragma unroll
      for (int r = 0; r < 4; ++r) {
        float s = sf[j][r] * 0.125f;
        if (diag && (kvb * 64 + j * 16 + ln > q0 + kg * 4 + r)) s = -1e30f;
        sf[j][r] = s;
      }

    // online softmax; row lives in the 16 lanes sharing kg
#pragma unroll
    for (int r = 0; r < 4; ++r) {
      float mx = fmaxf(fmaxf(sf[0][r], sf[1][r]), fmaxf(sf[2][r], sf[3][r]));
      mx = fmaxf(mx, __shfl_xor(mx, 1));
      mx = fmaxf(mx, __shfl_xor(mx, 2));
      mx = fmaxf(mx, __shfl_xor(mx, 4));
      mx = fmaxf(mx, __shfl_xor(mx, 8));
      float mnew = fmaxf(m_run[r], mx);
      alpha[r] = __expf(m_run[r] - mnew);
      m_run[r] = mnew;
      float rs = 0.f;
#pragma unroll
      for (int j = 0; j < 4; ++j) {
        float p = __expf(sf[j][r] - mnew);
        sf[j][r] = p;
        rs += p;
      }
      rs += __shfl_xor(rs, 1);
      rs += __shfl_xor(rs, 2);
      rs += __shfl_xor(rs, 4);
      rs += __shfl_xor(rs, 8);
      l_run[r] = l_run[r] * alpha[r] + rs;
    }

    // P -> per-wave LDS (bf16, col-block swizzled by f(q)=(q>>2)&3; here =kg)
#pragma unroll
    for (int j = 0; j < 4; ++j) {
      int js = j ^ kg;
#pragma unroll
      for (int r = 0; r < 4; ++r)
        myP[(kg * 4 + r) * 64 + js * 16 + ln] = f2bf(sf[j][r]);
    }
    asm volatile("s_waitcnt lgkmcnt(0)" ::: "memory");

#pragma unroll
    for (int dj = 0; dj < 4; ++dj)
#pragma unroll
      for (int r = 0; r < 4; ++r) acc_o[dj][r] *= alpha[r];

    // PV: A=P (q=ln, kv=kg*8+i (+32)), B=V^T rows d
    bf16x8 pa0 = *(const bf16x8*)&myP[ln * 64 + (((kg >> 1) ^ fql) * 16) + ((kg & 1) * 8)];
    bf16x8 pa1 = *(const bf16x8*)&myP[ln * 64 + (((2 + (kg >> 1)) ^ fql) * 16) + ((kg & 1) * 8)];
#pragma unroll
    for (int dj = 0; dj < 4; ++dj) {
      int d  = dj * 16 + ln;
      int fd = (d & 7) ^ ((d >> 3) & 7);
      bf16x8 vb0 = *(const bf16x8*)&Vs[d * 64 + ((kg ^ fd) * 8)];
      bf16x8 vb1 = *(const bf16x8*)&Vs[d * 64 + (((4 + kg) ^ fd) * 8)];
      acc_o[dj] = __builtin_amdgcn_mfma_f32_16x16x32_bf16(pa0, vb0, acc_o[dj], 0, 0, 0);
      acc_o[dj] = __builtin_amdgcn_mfma_f32_16x16x32_bf16(pa1, vb1, acc_o[dj], 0, 0, 0);
    }
    __syncthreads();
  }

#pragma unroll
  for (int dj = 0; dj < 4; ++dj)
#pragma unroll
    for (int r = 0; r < 4; ++r) {
      int q = q0 + kg * 4 + r;
      float v = acc_o[dj][r] / l_run[r];
      O[base + (size_t)q * ND + dj * 16 + ln] = f2bf(v);
    }
}

// ---------------------------------------------------------------- launcher
extern "C" void kernel_launch(void* const* d_in, const int* in_sizes, int n_in,
                              void* d_out, int out_size, void* d_ws, size_t ws_size,
                              hipStream_t stream) {
  const float* x  = (const float*)d_in[0];
  const int*   tp = (const int*)d_in[1];
  const float* Wq = (const float*)d_in[2];
  const float* Wk = (const float*)d_in[3];
  const float* Wv = (const float*)d_in[4];
  const float* Wo = (const float*)d_in[5];
  float* out = (float*)d_out;

  const size_t MD2 = (size_t)NM * ND * 2;  // 16 MiB
  const size_t WW2 = (size_t)ND * ND * 2;  //  2 MiB
  char* w = (char*)d_ws;
  unsigned short* xb  = (unsigned short*)w; w += MD2;
  unsigned short* Qt  = (unsigned short*)w; w += MD2;
  unsigned short* Kt  = (unsigned short*)w; w += MD2;
  unsigned short* Vt  = (unsigned short*)w; w += MD2;
  unsigned short* Wqb = (unsigned short*)w; w += WW2;
  unsigned short* Wkb = (unsigned short*)w; w += WW2;
  unsigned short* Wvb = (unsigned short*)w; w += WW2;
  unsigned short* Wob = (unsigned short*)w; w += WW2;
  unsigned short* Ot  = xb;  // alias: xb is dead after the QKV GEMM

  cast_bf16<<<dim3(8192), 256, 0, stream>>>(x,  xb,  NM * ND / 4);
  cast_bf16<<<dim3(1024), 256, 0, stream>>>(Wq, Wqb, ND * ND / 4);
  cast_bf16<<<dim3(1024), 256, 0, stream>>>(Wk, Wkb, ND * ND / 4);
  cast_bf16<<<dim3(1024), 256, 0, stream>>>(Wv, Wvb, ND * ND / 4);
  cast_bf16<<<dim3(1024), 256, 0, stream>>>(Wo, Wob, ND * ND / 4);
  gemm_qkv<<<dim3(8, 64, 3), 256, 0, stream>>>(xb, Wqb, Wkb, Wvb, tp, Qt, Kt, Vt);
  attn_kernel<<<dim3(32, 64), 256, 0, stream>>>(Qt, Kt, Vt, Ot);
  gemm_out<<<dim3(8, 64), 256, 0, stream>>>(Ot, Wob, out);
}

// Round 2
// 268.356 us; speedup vs baseline: 1.4661x; 1.4661x over previous
//
#include <hip/hip_runtime.h>
#include <stdint.h>

#define NB 4
#define NS 2048
#define ND 1024
#define NH 16
#define NM 8192   // NB*NS

typedef __attribute__((ext_vector_type(4))) float          f32x4;
typedef __attribute__((ext_vector_type(8))) __bf16         bf16x8;
typedef __attribute__((ext_vector_type(8))) unsigned short u16x8;
typedef __attribute__((ext_vector_type(4))) unsigned short u16x4;

static __device__ __forceinline__ unsigned short f2bf(float f) {
  unsigned u = __builtin_bit_cast(unsigned, f);
  return (unsigned short)((u + 0x7fffu + ((u >> 16) & 1u)) >> 16);
}

static __device__ __forceinline__ void gld_lds16(const void* g, void* l) {
  __builtin_amdgcn_global_load_lds((const __attribute__((address_space(1))) void*)g,
                                   (__attribute__((address_space(3))) void*)l, 16, 0, 0);
}

// ---------------------------------------------------------------- cast f32->bf16
__global__ __launch_bounds__(256) void cast_bf16(const float* __restrict__ in,
                                                 unsigned short* __restrict__ out,
                                                 int n4) {
  int i = blockIdx.x * 256 + threadIdx.x;
  if (i >= n4) return;
  f32x4 v = ((const f32x4*)in)[i];
  u16x4 o;
#pragma unroll
  for (int e = 0; e < 4; ++e) o[e] = f2bf(v[e]);
  ((u16x4*)out)[i] = o;
}

// all four weight matrices in one launch (blockIdx.y selects)
__global__ __launch_bounds__(256) void cast_w4(
    const float* __restrict__ a, const float* __restrict__ b,
    const float* __restrict__ c, const float* __restrict__ d,
    unsigned short* __restrict__ oa, unsigned short* __restrict__ ob,
    unsigned short* __restrict__ oc, unsigned short* __restrict__ od) {
  int z = blockIdx.y;
  const float* in = (z == 0) ? a : (z == 1) ? b : (z == 2) ? c : d;
  unsigned short* out = (z == 0) ? oa : (z == 1) ? ob : (z == 2) ? oc : od;
  int i = blockIdx.x * 256 + threadIdx.x;
  f32x4 v = ((const f32x4*)in)[i];
  u16x4 o;
#pragma unroll
  for (int e = 0; e < 4; ++e) o[e] = f2bf(v[e]);
  ((u16x4*)out)[i] = o;
}

// ---------------------------------------------------------------- 128x128 NT GEMM
template<bool OUTF32>
static __device__ __forceinline__ void gemm_body(
    const unsigned short* __restrict__ A,
    const unsigned short* __restrict__ Bw,
    const int* __restrict__ tp,
    void* __restrict__ Cout,
    bool rope)
{
  __shared__ unsigned short As[128 * 32];
  __shared__ unsigned short Bs[128 * 32];

  const int tid  = threadIdx.x;
  const int wid  = tid >> 6, lane = tid & 63;
  const int ln   = lane & 15, kg = lane >> 4;
  const int wr   = wid >> 1,  wc = wid & 1;
  const int m0   = blockIdx.y * 128, n0 = blockIdx.x * 128;

  const int c0 = tid, c1 = tid + 256;
  const int r0 = c0 >> 2, s0 = c0 & 3;
  const int r1 = c1 >> 2, s1 = c1 & 3;
  const int f0 = (r0 & 3) ^ ((r0 >> 2) & 3);
  const int f1 = (r1 & 3) ^ ((r1 >> 2) & 3);

  const unsigned short* gA0 = A  + (size_t)(m0 + r0) * ND + ((s0 ^ f0) * 8);
  const unsigned short* gA1 = A  + (size_t)(m0 + r1) * ND + ((s1 ^ f1) * 8);
  const unsigned short* gB0 = Bw + (size_t)(n0 + r0) * ND + ((s0 ^ f0) * 8);
  const unsigned short* gB1 = Bw + (size_t)(n0 + r1) * ND + ((s1 ^ f1) * 8);

  unsigned short* lA0 = &As[(wid * 64) * 8];
  unsigned short* lA1 = &As[(256 + wid * 64) * 8];
  unsigned short* lB0 = &Bs[(wid * 64) * 8];
  unsigned short* lB1 = &Bs[(256 + wid * 64) * 8];

  const int fql = (ln & 3) ^ ((ln >> 2) & 3);
  int offA[4], offB[4];
#pragma unroll
  for (int i = 0; i < 4; ++i) {
    offA[i] = (wr * 64 + i * 16 + ln) * 32 + ((kg ^ fql) * 8);
    offB[i] = (wc * 64 + i * 16 + ln) * 32 + ((kg ^ fql) * 8);
  }

  f32x4 acc[4][4];
#pragma unroll
  for (int i = 0; i < 4; ++i)
#pragma unroll
    for (int j = 0; j < 4; ++j) acc[i][j] = (f32x4){0.f, 0.f, 0.f, 0.f};

  for (int kt = 0; kt < 32; ++kt) {
    gld_lds16(gA0, lA0);
    gld_lds16(gA1, lA1);
    gld_lds16(gB0, lB0);
    gld_lds16(gB1, lB1);
    gA0 += 32; gA1 += 32; gB0 += 32; gB1 += 32;
    __syncthreads();
    bf16x8 af[4], bfr[4];
#pragma unroll
    for (int i = 0; i < 4; ++i) af[i] = *(const bf16x8*)&As[offA[i]];
#pragma unroll
    for (int j = 0; j < 4; ++j) bfr[j] = *(const bf16x8*)&Bs[offB[j]];
#pragma unroll
    for (int i = 0; i < 4; ++i)
#pragma unroll
      for (int j = 0; j < 4; ++j)
        acc[i][j] = __builtin_amdgcn_mfma_f32_16x16x32_bf16(af[i], bfr[j], acc[i][j], 0, 0, 0);
    __syncthreads();
  }

  if (OUTF32) {
    float* C = (float*)Cout;
#pragma unroll
    for (int i = 0; i < 4; ++i)
#pragma unroll
      for (int j = 0; j < 4; ++j)
#pragma unroll
        for (int r = 0; r < 4; ++r) {
          int m = m0 + wr * 64 + i * 16 + kg * 4 + r;
          int n = n0 + wc * 64 + j * 16 + ln;
          C[(size_t)m * ND + n] = acc[i][j][r];
        }
  } else {
    unsigned short* C = (unsigned short*)Cout;
#pragma unroll
    for (int i = 0; i < 4; ++i)
#pragma unroll
      for (int r = 0; r < 4; ++r) {
        int m = m0 + wr * 64 + i * 16 + kg * 4 + r;
        float pos = rope ? (float)tp[m] : 0.f;
#pragma unroll
        for (int j = 0; j < 4; ++j) {
          int n = n0 + wc * 64 + j * 16 + ln;
          float v  = acc[i][j][r];
          float pv = __shfl_xor(v, 1);
          float outv = v;
          if (rope) {
            int   ip   = (n & 63) >> 1;
            float invf = __expf(-0.28782313662425572f * (float)ip);
            float ang  = pos * invf;
            float sn, cs;
            __sincosf(ang, &sn, &cs);
            outv = (n & 1) ? (pv * sn + v * cs) : (v * cs - pv * sn);
          }
          C[(size_t)m * ND + n] = f2bf(outv);
        }
      }
  }
}

__global__ __launch_bounds__(256) void gemm_qkv(
    const unsigned short* __restrict__ xb,
    const unsigned short* __restrict__ Wqb,
    const unsigned short* __restrict__ Wkb,
    const unsigned short* __restrict__ Wvb,
    const int* __restrict__ tp,
    unsigned short* __restrict__ Qt,
    unsigned short* __restrict__ Kt,
    unsigned short* __restrict__ Vt)
{
  int z = blockIdx.z;
  const unsigned short* Bw = (z == 0) ? Wqb : (z == 1) ? Wkb : Wvb;
  unsigned short* C        = (z == 0) ? Qt  : (z == 1) ? Kt  : Vt;
  gemm_body<false>(xb, Bw, tp, C, z < 2);
}

__global__ __launch_bounds__(256) void gemm_out(
    const unsigned short* __restrict__ Ot,
    const unsigned short* __restrict__ Wob,
    float* __restrict__ C)
{
  gemm_body<true>(Ot, Wob, nullptr, C, false);
}

// ---------------------------------------------------------------- V transpose
// Vt [b][s][h*64+d] -> Vt2 [b*16+h][d][s]   (64x64 tiles via LDS)
__global__ __launch_bounds__(256) void transpose_v(
    const unsigned short* __restrict__ Vt,
    unsigned short* __restrict__ Vt2)
{
  __shared__ unsigned short T[64][72];
  const int bh = blockIdx.y;
  const int s0 = blockIdx.x * 64;
  const int b  = bh >> 4, h = bh & 15;
  const int tid = threadIdx.x;

  const unsigned short* src = Vt + (size_t)b * NS * ND + (size_t)s0 * ND + h * 64;
#pragma unroll
  for (int c = tid; c < 512; c += 256) {
    int r = c >> 3, c8 = c & 7;
    u16x8 v = *(const u16x8*)(src + (size_t)r * ND + c8 * 8);
#pragma unroll
    for (int e = 0; e < 8; ++e) T[r][c8 * 8 + e] = v[e];
  }
  __syncthreads();
  unsigned short* dst = Vt2 + (size_t)bh * 64 * NS + s0;
#pragma unroll
  for (int c = tid; c < 512; c += 256) {
    int d = c >> 3, sc = c & 7;
    u16x8 v;
#pragma unroll
    for (int e = 0; e < 8; ++e) v[e] = T[sc * 8 + e][d];
    *(u16x8*)(dst + (size_t)d * NS + sc * 8) = v;
  }
}

// ---------------------------------------------------------------- flash attention
// grid (16 qb-pairs, 64 bh). 256 thr = 4 waves x 16 q-rows. KV tiles of 64.
// Q,K [b][s][h*64+d]; Vt2 [bh][d][s]; O [b][s][h*64+d]. Causal, scale 1/8.
// 2-phase pipeline: stage tile t+1 before computing tile t (double-buffered LDS).
__global__ __launch_bounds__(256) void attn_kernel(
    const unsigned short* __restrict__ Q,
    const unsigned short* __restrict__ K,
    const unsigned short* __restrict__ Vt2,
    unsigned short* __restrict__ O)
{
  __shared__ unsigned short Ks[2][64 * 64];
  __shared__ unsigned short Vs[2][64 * 64];   // V^T tile: [d][kv], source-swizzled
  __shared__ unsigned short Ps[4][16 * 64];

  const int tid = threadIdx.x;
  const int wid = tid >> 6, lane = tid & 63;
  const int ln  = lane & 15, kg = lane >> 4;
  const int bh  = blockIdx.y;
  const int b   = bh >> 4, h = bh & 15;

  const size_t base  = (size_t)b * NS * ND + (size_t)h * 64;
  const size_t vbase = (size_t)bh * 64 * NS;

  // staging chunk coords (chunks c = tid, tid+256): row = c>>3, slot = c&7
  const int cA = tid,      cB = tid + 256;
  const int rA = cA >> 3,  slA = cA & 7;
  const int rB = cB >> 3,  slB = cB & 7;

  const unsigned short* KgA = K + base + (size_t)rA * ND + ((slA ^ (rA & 7)) * 8);
  const unsigned short* KgB = K + base + (size_t)rB * ND + ((slB ^ (rB & 7)) * 8);
  const unsigned short* VgA = Vt2 + vbase + (size_t)rA * NS + ((slA ^ (rA & 7)) * 8);
  const unsigned short* VgB = Vt2 + vbase + (size_t)rB * NS + ((slB ^ (rB & 7)) * 8);

  const int ldsOffA = wid * 512 + lane * 8;        // chunk tid
  const int ldsOffB = 2048 + wid * 512 + lane * 8; // chunk tid+256

  unsigned short* myP = &Ps[wid][0];
  const int fql = (ln >> 2) & 3;

  int qbs0 = blockIdx.x, qbs1 = 31 - blockIdx.x;

  for (int pi = 0; pi < 2; ++pi) {
    const int qb = pi ? qbs1 : qbs0;
    const int nt = qb + 1;
    const int q0 = qb * 64 + wid * 16;

    bf16x8 qf[2];
    {
      const unsigned short* qp = Q + base + (size_t)(q0 + ln) * ND + kg * 8;
      qf[0] = *(const bf16x8*)qp;
      qf[1] = *(const bf16x8*)(qp + 32);
    }

    float m_run[4], l_run[4], alpha[4];
    f32x4 acc_o[4];
#pragma unroll
    for (int r = 0; r < 4; ++r) { m_run[r] = -1e30f; l_run[r] = 0.f; }
#pragma unroll
    for (int dj = 0; dj < 4; ++dj) acc_o[dj] = (f32x4){0.f, 0.f, 0.f, 0.f};

    // prologue: stage tile 0 into buf 0
    {
      gld_lds16(KgA, &Ks[0][ldsOffA]);
      gld_lds16(KgB, &Ks[0][ldsOffB]);
      gld_lds16(VgA, &Vs[0][ldsOffA]);
      gld_lds16(VgB, &Vs[0][ldsOffB]);
    }
    __syncthreads();

    for (int t = 0; t < nt; ++t) {
      const int buf = t & 1;
      // stage next tile into the other buffer (overlaps with compute below)
      if (t + 1 < nt) {
        const size_t ko = (size_t)(t + 1) * 64 * ND;
        const int    vo = (t + 1) * 64;
        const int nb = buf ^ 1;
        gld_lds16(KgA + ko, &Ks[nb][ldsOffA]);
        gld_lds16(KgB + ko, &Ks[nb][ldsOffB]);
        gld_lds16(VgA + vo, &Vs[nb][ldsOffA]);
        gld_lds16(VgB + vo, &Vs[nb][ldsOffB]);
      }

      // ---- S = Q K^T
      f32x4 sf[4];
#pragma unroll
      for (int j = 0; j < 4; ++j) {
        int kvr = j * 16 + ln;
        bf16x8 k0 = *(const bf16x8*)&Ks[buf][kvr * 64 + ((kg ^ (kvr & 7)) * 8)];
        bf16x8 k1 = *(const bf16x8*)&Ks[buf][kvr * 64 + (((4 + kg) ^ (kvr & 7)) * 8)];
        f32x4 z = (f32x4){0.f, 0.f, 0.f, 0.f};
        z = __builtin_amdgcn_mfma_f32_16x16x32_bf16(qf[0], k0, z, 0, 0, 0);
        z = __builtin_amdgcn_mfma_f32_16x16x32_bf16(qf[1], k1, z, 0, 0, 0);
        sf[j] = z;
      }

      const bool diag = (t == qb);
#pragma unroll
      for (int j = 0; j < 4; ++j)
#pragma unroll
        for (int r = 0; r < 4; ++r) {
          float s = sf[j][r] * 0.125f;
          if (diag && (t * 64 + j * 16 + ln > q0 + kg * 4 + r)) s = -1e30f;
          sf[j][r] = s;
        }

      // ---- online softmax (row = 16 lanes sharing kg)
#pragma unroll
      for (int r = 0; r < 4; ++r) {
        float mx = fmaxf(fmaxf(sf[0][r], sf[1][r]), fmaxf(sf[2][r], sf[3][r]));
        mx = fmaxf(mx, __shfl_xor(mx, 1));
        mx = fmaxf(mx, __shfl_xor(mx, 2));
        mx = fmaxf(mx, __shfl_xor(mx, 4));
        mx = fmaxf(mx, __shfl_xor(mx, 8));
        float mnew = fmaxf(m_run[r], mx);
        alpha[r] = __expf(m_run[r] - mnew);
        m_run[r] = mnew;
        float rs = 0.f;
#pragma unroll
        for (int j = 0; j < 4; ++j) {
          float p = __expf(sf[j][r] - mnew);
          sf[j][r] = p;
          rs += p;
        }
        rs += __shfl_xor(rs, 1);
        rs += __shfl_xor(rs, 2);
        rs += __shfl_xor(rs, 4);
        rs += __shfl_xor(rs, 8);
        l_run[r] = l_run[r] * alpha[r] + rs;
      }

      // ---- P -> per-wave LDS (col-block swizzled by kg)
#pragma unroll
      for (int j = 0; j < 4; ++j) {
        int js = j ^ kg;
#pragma unroll
        for (int r = 0; r < 4; ++r)
          myP[(kg * 4 + r) * 64 + js * 16 + ln] = f2bf(sf[j][r]);
      }
      asm volatile("s_waitcnt lgkmcnt(0)" ::: "memory");
      __builtin_amdgcn_sched_barrier(0);

#pragma unroll
      for (int dj = 0; dj < 4; ++dj)
#pragma unroll
        for (int r = 0; r < 4; ++r) acc_o[dj][r] *= alpha[r];

      // ---- PV
      bf16x8 pa0 = *(const bf16x8*)&myP[ln * 64 + (((kg >> 1) ^ fql) * 16) + ((kg & 1) * 8)];
      bf16x8 pa1 = *(const bf16x8*)&myP[ln * 64 + (((2 + (kg >> 1)) ^ fql) * 16) + ((kg & 1) * 8)];
#pragma unroll
      for (int dj = 0; dj < 4; ++dj) {
        int d  = dj * 16 + ln;
        bf16x8 vb0 = *(const bf16x8*)&Vs[buf][d * 64 + ((kg ^ (d & 7)) * 8)];
        bf16x8 vb1 = *(const bf16x8*)&Vs[buf][d * 64 + (((4 + kg) ^ (d & 7)) * 8)];
        acc_o[dj] = __builtin_amdgcn_mfma_f32_16x16x32_bf16(pa0, vb0, acc_o[dj], 0, 0, 0);
        acc_o[dj] = __builtin_amdgcn_mfma_f32_16x16x32_bf16(pa1, vb1, acc_o[dj], 0, 0, 0);
      }
      __syncthreads();   // drains vmcnt (next-tile stage) + all waves done with buf
    }

#pragma unroll
    for (int dj = 0; dj < 4; ++dj)
#pragma unroll
      for (int r = 0; r < 4; ++r) {
        int q = q0 + kg * 4 + r;
        float v = acc_o[dj][r] / l_run[r];
        O[base + (size_t)q * ND + dj * 16 + ln] = f2bf(v);
      }
  }
}

// ---------------------------------------------------------------- launcher
extern "C" void kernel_launch(void* const* d_in, const int* in_sizes, int n_in,
                              void* d_out, int out_size, void* d_ws, size_t ws_size,
                              hipStream_t stream) {
  const float* x  = (const float*)d_in[0];
  const int*   tp = (const int*)d_in[1];
  const float* Wq = (const float*)d_in[2];
  const float* Wk = (const float*)d_in[3];
  const float* Wv = (const float*)d_in[4];
  const float* Wo = (const float*)d_in[5];
  float* out = (float*)d_out;

  const size_t MD2 = (size_t)NM * ND * 2;  // 16 MiB
  const size_t WW2 = (size_t)ND * ND * 2;  //  2 MiB
  char* w = (char*)d_ws;
  unsigned short* xb  = (unsigned short*)w; w += MD2;
  unsigned short* Qt  = (unsigned short*)w; w += MD2;
  unsigned short* Kt  = (unsigned short*)w; w += MD2;
  unsigned short* Vt  = (unsigned short*)w; w += MD2;
  unsigned short* Wqb = (unsigned short*)w; w += WW2;
  unsigned short* Wkb = (unsigned short*)w; w += WW2;
  unsigned short* Wvb = (unsigned short*)w; w += WW2;
  unsigned short* Wob = (unsigned short*)w; w += WW2;
  unsigned short* Vt2 = xb;  // alias: xb dead after gemm_qkv
  unsigned short* Ot  = Vt;  // alias: Vt dead after transpose_v

  cast_bf16<<<dim3(8192), 256, 0, stream>>>(x, xb, NM * ND / 4);
  cast_w4<<<dim3(1024, 4), 256, 0, stream>>>(Wq, Wk, Wv, Wo, Wqb, Wkb, Wvb, Wob);
  gemm_qkv<<<dim3(8, 64, 3), 256, 0, stream>>>(xb, Wqb, Wkb, Wvb, tp, Qt, Kt, Vt);
  transpose_v<<<dim3(32, 64), 256, 0, stream>>>(Vt, Vt2);
  attn_kernel<<<dim3(16, 64), 256, 0, stream>>>(Qt, Kt, Vt2, Ot);
  gemm_out<<<dim3(8, 64), 256, 0, stream>>>(Ot, Wob, out);
}

// Round 3
// 232.692 us; speedup vs baseline: 1.6908x; 1.1533x over previous
//
#include <hip/hip_runtime.h>
#include <stdint.h>

#define NB 4
#define NS 2048
#define ND 1024
#define NH 16
#define NM 8192   // NB*NS

typedef __attribute__((ext_vector_type(4))) float          f32x4;
typedef __attribute__((ext_vector_type(8))) __bf16         bf16x8;
typedef __attribute__((ext_vector_type(8))) unsigned short u16x8;
typedef __attribute__((ext_vector_type(4))) unsigned short u16x4;

static __device__ __forceinline__ unsigned short f2bf(float f) {
  unsigned u = __builtin_bit_cast(unsigned, f);
  return (unsigned short)((u + 0x7fffu + ((u >> 16) & 1u)) >> 16);
}

#if __has_builtin(__builtin_amdgcn_exp2f)
#define EX2(x) __builtin_amdgcn_exp2f(x)
#else
#define EX2(x) __expf((x) * 0.69314718056f)
#endif
#if __has_builtin(__builtin_amdgcn_rcpf)
#define RCP(x) __builtin_amdgcn_rcpf(x)
#else
#define RCP(x) (1.0f / (x))
#endif

static __device__ __forceinline__ unsigned cvtpk(float lo, float hi) {
  unsigned r;
  asm("v_cvt_pk_bf16_f32 %0, %1, %2" : "=v"(r) : "v"(lo), "v"(hi));
  return r;
}

static __device__ __forceinline__ void gld_lds16(const void* g, void* l) {
  __builtin_amdgcn_global_load_lds((const __attribute__((address_space(1))) void*)g,
                                   (__attribute__((address_space(3))) void*)l, 16, 0, 0);
}

// ---------------------------------------------------------------- cast f32->bf16
__global__ __launch_bounds__(256) void cast_bf16(const float* __restrict__ in,
                                                 unsigned short* __restrict__ out,
                                                 int n4) {
  int i = blockIdx.x * 256 + threadIdx.x;
  if (i >= n4) return;
  f32x4 v = ((const f32x4*)in)[i];
  u16x4 o;
#pragma unroll
  for (int e = 0; e < 4; ++e) o[e] = f2bf(v[e]);
  ((u16x4*)out)[i] = o;
}

__global__ __launch_bounds__(256) void cast_w4(
    const float* __restrict__ a, const float* __restrict__ b,
    const float* __restrict__ c, const float* __restrict__ d,
    unsigned short* __restrict__ oa, unsigned short* __restrict__ ob,
    unsigned short* __restrict__ oc, unsigned short* __restrict__ od) {
  int z = blockIdx.y;
  const float* in = (z == 0) ? a : (z == 1) ? b : (z == 2) ? c : d;
  unsigned short* out = (z == 0) ? oa : (z == 1) ? ob : (z == 2) ? oc : od;
  int i = blockIdx.x * 256 + threadIdx.x;
  f32x4 v = ((const f32x4*)in)[i];
  u16x4 o;
#pragma unroll
  for (int e = 0; e < 4; ++e) o[e] = f2bf(v[e]);
  ((u16x4*)out)[i] = o;
}

// ---------------------------------------------------------------- 128x128 NT GEMM
template<bool OUTF32>
static __device__ __forceinline__ void gemm_body(
    const unsigned short* __restrict__ A,
    const unsigned short* __restrict__ Bw,
    const int* __restrict__ tp,
    void* __restrict__ Cout,
    bool rope)
{
  __shared__ unsigned short As[128 * 32];
  __shared__ unsigned short Bs[128 * 32];

  const int tid  = threadIdx.x;
  const int wid  = tid >> 6, lane = tid & 63;
  const int ln   = lane & 15, kg = lane >> 4;
  const int wr   = wid >> 1,  wc = wid & 1;

  // XCD-aware swizzle (T1): 512 WGs per z-slice, nwg%8==0 -> bijective
  const int idw = blockIdx.y * gridDim.x + blockIdx.x;
  const int swz = (idw & 7) * 64 + (idw >> 3);
  const int m0  = (swz >> 3) * 128, n0 = (swz & 7) * 128;

  const int c0 = tid, c1 = tid + 256;
  const int r0 = c0 >> 2, s0 = c0 & 3;
  const int r1 = c1 >> 2, s1 = c1 & 3;
  const int f0 = (r0 & 3) ^ ((r0 >> 2) & 3);
  const int f1 = (r1 & 3) ^ ((r1 >> 2) & 3);

  const unsigned short* gA0 = A  + (size_t)(m0 + r0) * ND + ((s0 ^ f0) * 8);
  const unsigned short* gA1 = A  + (size_t)(m0 + r1) * ND + ((s1 ^ f1) * 8);
  const unsigned short* gB0 = Bw + (size_t)(n0 + r0) * ND + ((s0 ^ f0) * 8);
  const unsigned short* gB1 = Bw + (size_t)(n0 + r1) * ND + ((s1 ^ f1) * 8);

  unsigned short* lA0 = &As[(wid * 64) * 8];
  unsigned short* lA1 = &As[(256 + wid * 64) * 8];
  unsigned short* lB0 = &Bs[(wid * 64) * 8];
  unsigned short* lB1 = &Bs[(256 + wid * 64) * 8];

  const int fql = (ln & 3) ^ ((ln >> 2) & 3);
  int offA[4], offB[4];
#pragma unroll
  for (int i = 0; i < 4; ++i) {
    offA[i] = (wr * 64 + i * 16 + ln) * 32 + ((kg ^ fql) * 8);
    offB[i] = (wc * 64 + i * 16 + ln) * 32 + ((kg ^ fql) * 8);
  }

  f32x4 acc[4][4];
#pragma unroll
  for (int i = 0; i < 4; ++i)
#pragma unroll
    for (int j = 0; j < 4; ++j) acc[i][j] = (f32x4){0.f, 0.f, 0.f, 0.f};

  for (int kt = 0; kt < 32; ++kt) {
    gld_lds16(gA0, lA0);
    gld_lds16(gA1, lA1);
    gld_lds16(gB0, lB0);
    gld_lds16(gB1, lB1);
    gA0 += 32; gA1 += 32; gB0 += 32; gB1 += 32;
    __syncthreads();
    bf16x8 af[4], bfr[4];
#pragma unroll
    for (int i = 0; i < 4; ++i) af[i] = *(const bf16x8*)&As[offA[i]];
#pragma unroll
    for (int j = 0; j < 4; ++j) bfr[j] = *(const bf16x8*)&Bs[offB[j]];
    __builtin_amdgcn_s_setprio(1);
#pragma unroll
    for (int i = 0; i < 4; ++i)
#pragma unroll
      for (int j = 0; j < 4; ++j)
        acc[i][j] = __builtin_amdgcn_mfma_f32_16x16x32_bf16(af[i], bfr[j], acc[i][j], 0, 0, 0);
    __builtin_amdgcn_s_setprio(0);
    __syncthreads();
  }

  if (OUTF32) {
    float* C = (float*)Cout;
#pragma unroll
    for (int i = 0; i < 4; ++i)
#pragma unroll
      for (int j = 0; j < 4; ++j)
#pragma unroll
        for (int r = 0; r < 4; ++r) {
          int m = m0 + wr * 64 + i * 16 + kg * 4 + r;
          int n = n0 + wc * 64 + j * 16 + ln;
          C[(size_t)m * ND + n] = acc[i][j][r];
        }
  } else {
    unsigned short* C = (unsigned short*)Cout;
#pragma unroll
    for (int i = 0; i < 4; ++i)
#pragma unroll
      for (int r = 0; r < 4; ++r) {
        int m = m0 + wr * 64 + i * 16 + kg * 4 + r;
        float pos = rope ? (float)tp[m] : 0.f;
#pragma unroll
        for (int j = 0; j < 4; ++j) {
          int n = n0 + wc * 64 + j * 16 + ln;
          float v  = acc[i][j][r];
          float pv = __shfl_xor(v, 1);
          float outv = v;
          if (rope) {
            int   ip   = (n & 63) >> 1;
            float invf = __expf(-0.28782313662425572f * (float)ip);
            float ang  = pos * invf;
            float sn, cs;
            __sincosf(ang, &sn, &cs);
            outv = (n & 1) ? (pv * sn + v * cs) : (v * cs - pv * sn);
          }
          C[(size_t)m * ND + n] = f2bf(outv);
        }
      }
  }
}

__global__ __launch_bounds__(256) void gemm_qkv(
    const unsigned short* __restrict__ xb,
    const unsigned short* __restrict__ Wqb,
    const unsigned short* __restrict__ Wkb,
    const unsigned short* __restrict__ Wvb,
    const int* __restrict__ tp,
    unsigned short* __restrict__ Qt,
    unsigned short* __restrict__ Kt,
    unsigned short* __restrict__ Vt)
{
  int z = blockIdx.z;
  const unsigned short* Bw = (z == 0) ? Wqb : (z == 1) ? Wkb : Wvb;
  unsigned short* C        = (z == 0) ? Qt  : (z == 1) ? Kt  : Vt;
  gemm_body<false>(xb, Bw, tp, C, z < 2);
}

__global__ __launch_bounds__(256) void gemm_out(
    const unsigned short* __restrict__ Ot,
    const unsigned short* __restrict__ Wob,
    float* __restrict__ C)
{
  gemm_body<true>(Ot, Wob, nullptr, C, false);
}

// ---------------------------------------------------------------- V transpose
__global__ __launch_bounds__(256) void transpose_v(
    const unsigned short* __restrict__ Vt,
    unsigned short* __restrict__ Vt2)
{
  __shared__ unsigned short T[64][72];
  const int bh = blockIdx.y;
  const int s0 = blockIdx.x * 64;
  const int b  = bh >> 4, h = bh & 15;
  const int tid = threadIdx.x;

  const unsigned short* src = Vt + (size_t)b * NS * ND + (size_t)s0 * ND + h * 64;
#pragma unroll
  for (int c = tid; c < 512; c += 256) {
    int r = c >> 3, c8 = c & 7;
    u16x8 v = *(const u16x8*)(src + (size_t)r * ND + c8 * 8);
#pragma unroll
    for (int e = 0; e < 8; ++e) T[r][c8 * 8 + e] = v[e];
  }
  __syncthreads();
  unsigned short* dst = Vt2 + (size_t)bh * 64 * NS + s0;
#pragma unroll
  for (int c = tid; c < 512; c += 256) {
    int d = c >> 3, sc = c & 7;
    u16x8 v;
#pragma unroll
    for (int e = 0; e < 8; ++e) v[e] = T[sc * 8 + e][d];
    *(u16x8*)(dst + (size_t)d * NS + sc * 8) = v;
  }
}

// ---------------------------------------------------------------- flash attention
// Swapped-operand layout: S^T = K·Q^T so each lane owns ONE q-row (q = ln).
// grid (16 qb-pairs, 64 bh). 4 waves x 16 q-rows. KV tiles of 64, 2-phase dbuf.
__global__ __launch_bounds__(256, 4) void attn_kernel(
    const unsigned short* __restrict__ Q,
    const unsigned short* __restrict__ K,
    const unsigned short* __restrict__ Vt2,
    unsigned short* __restrict__ O)
{
  __shared__ unsigned short Ks[2][64 * 64];
  __shared__ unsigned short Vs[2][64 * 64];
  __shared__ unsigned long long Pw[4][256];   // per-wave 2KB P/O staging

  const int tid = threadIdx.x;
  const int wid = tid >> 6, lane = tid & 63;
  const int ln  = lane & 15, kg = lane >> 4;
  const int bh  = blockIdx.y;
  const int b   = bh >> 4, h = bh & 15;

  const size_t base  = (size_t)b * NS * ND + (size_t)h * 64;
  const size_t vbase = (size_t)bh * 64 * NS;

  const int cA = tid,      cB = tid + 256;
  const int rA = cA >> 3,  slA = cA & 7;
  const int rB = cB >> 3,  slB = cB & 7;

  const unsigned short* KgA = K + base + (size_t)rA * ND + ((slA ^ (rA & 7)) * 8);
  const unsigned short* KgB = K + base + (size_t)rB * ND + ((slB ^ (rB & 7)) * 8);
  const unsigned short* VgA = Vt2 + vbase + (size_t)rA * NS + ((slA ^ (rA & 7)) * 8);
  const unsigned short* VgB = Vt2 + vbase + (size_t)rB * NS + ((slB ^ (rB & 7)) * 8);

  const int ldsOffA = wid * 512 + lane * 8;
  const int ldsOffB = 2048 + wid * 512 + lane * 8;

  // per-wave P/O staging addresses (16B-granule XOR swizzle by ln&7)
  char* pwb = (char*)&Pw[wid][0];
  int wb[4];
#pragma unroll
  for (int j = 0; j < 4; ++j)
    wb[j] = ln * 128 + (((2 * j + (kg >> 1)) ^ (ln & 7)) << 4) + ((kg & 1) << 3);
  const int rb0 = ln * 128 + ((kg ^ (ln & 7)) << 4);
  const int rb1 = ln * 128 + (((4 + kg) ^ (ln & 7)) << 4);

  const float C2 = 0.18033688011111543f;  // 0.125 * log2(e)

  int qbs0 = blockIdx.x, qbs1 = 31 - blockIdx.x;

  for (int pi = 0; pi < 2; ++pi) {
    const int qb = pi ? qbs1 : qbs0;
    const int nt = qb + 1;
    const int q0 = qb * 64 + wid * 16;
    const int qloc = wid * 16 + ln;   // q - qb*64 for this lane's row

    bf16x8 qf[2];
    {
      const unsigned short* qp = Q + base + (size_t)(q0 + ln) * ND + kg * 8;
      qf[0] = *(const bf16x8*)qp;
      qf[1] = *(const bf16x8*)(qp + 32);
    }

    float m_run = -1e30f, l_run = 0.f;
    f32x4 acc_o[4];
#pragma unroll
    for (int dj = 0; dj < 4; ++dj) acc_o[dj] = (f32x4){0.f, 0.f, 0.f, 0.f};

    // prologue: stage tile 0 into buf 0
    gld_lds16(KgA, &Ks[0][ldsOffA]);
    gld_lds16(KgB, &Ks[0][ldsOffB]);
    gld_lds16(VgA, &Vs[0][ldsOffA]);
    gld_lds16(VgB, &Vs[0][ldsOffB]);
    __syncthreads();

    for (int t = 0; t < nt; ++t) {
      const int buf = t & 1;
      if (t + 1 < nt) {
        const size_t ko = (size_t)(t + 1) * 64 * ND;
        const int    vo = (t + 1) * 64;
        const int nb = buf ^ 1;
        gld_lds16(KgA + ko, &Ks[nb][ldsOffA]);
        gld_lds16(KgB + ko, &Ks[nb][ldsOffB]);
        gld_lds16(VgA + vo, &Vs[nb][ldsOffA]);
        gld_lds16(VgB + vo, &Vs[nb][ldsOffB]);
      }

      // ---- S^T = K·Q^T : st[j][r] = S^T[kv=16j+4kg+r][q=q0+ln]
      f32x4 st[4];
      __builtin_amdgcn_s_setprio(1);
#pragma unroll
      for (int j = 0; j < 4; ++j) {
        int kvr = j * 16 + ln;
        bf16x8 k0 = *(const bf16x8*)&Ks[buf][kvr * 64 + ((kg ^ (kvr & 7)) * 8)];
        bf16x8 k1 = *(const bf16x8*)&Ks[buf][kvr * 64 + (((4 + kg) ^ (kvr & 7)) * 8)];
        f32x4 z = (f32x4){0.f, 0.f, 0.f, 0.f};
        z = __builtin_amdgcn_mfma_f32_16x16x32_bf16(k0, qf[0], z, 0, 0, 0);
        z = __builtin_amdgcn_mfma_f32_16x16x32_bf16(k1, qf[1], z, 0, 0, 0);
        st[j] = z;
      }
      __builtin_amdgcn_s_setprio(0);

      // ---- scale to log2 domain + causal mask
#pragma unroll
      for (int j = 0; j < 4; ++j)
#pragma unroll
        for (int r = 0; r < 4; ++r) st[j][r] *= C2;
      if (t == qb) {
#pragma unroll
        for (int j = 0; j < 4; ++j)
#pragma unroll
          for (int r = 0; r < 4; ++r)
            if (16 * j + 4 * kg + r > qloc) st[j][r] = -1e30f;
      }

      // ---- row max: in-lane tree + 2 shfl (row replicated over 4 kg-lanes)
      float a0 = fmaxf(fmaxf(st[0][0], st[0][1]), fmaxf(st[0][2], st[0][3]));
      float a1 = fmaxf(fmaxf(st[1][0], st[1][1]), fmaxf(st[1][2], st[1][3]));
      float a2 = fmaxf(fmaxf(st[2][0], st[2][1]), fmaxf(st[2][2], st[2][3]));
      float a3 = fmaxf(fmaxf(st[3][0], st[3][1]), fmaxf(st[3][2], st[3][3]));
      float mx = fmaxf(fmaxf(a0, a1), fmaxf(a2, a3));
      mx = fmaxf(mx, __shfl_xor(mx, 16));
      mx = fmaxf(mx, __shfl_xor(mx, 32));

      // ---- defer-max (T13): rescale only if some row grew past threshold
      if (__any(mx > m_run + 11.0f)) {
        float mnew = fmaxf(m_run, mx);
        float alpha = EX2(m_run - mnew);
        m_run = mnew;
        l_run *= alpha;
#pragma unroll
        for (int dj = 0; dj < 4; ++dj)
#pragma unroll
          for (int r = 0; r < 4; ++r) acc_o[dj][r] *= alpha;
      }

      // ---- P = exp2(s - m)
#pragma unroll
      for (int j = 0; j < 4; ++j)
#pragma unroll
        for (int r = 0; r < 4; ++r) st[j][r] = EX2(st[j][r] - m_run);

      // ---- P -> per-wave LDS as [q=ln][kv] bf16 (cvt_pk pairs are kv-adjacent)
#pragma unroll
      for (int j = 0; j < 4; ++j) {
        unsigned w0 = cvtpk(st[j][0], st[j][1]);
        unsigned w1 = cvtpk(st[j][2], st[j][3]);
        *(unsigned long long*)(pwb + wb[j]) =
            (unsigned long long)w0 | ((unsigned long long)w1 << 32);
      }

      // ---- row sum (tree) + 2 shfl, overlaps with LDS write latency
      float s0s = (st[0][0] + st[0][1]) + (st[0][2] + st[0][3]);
      float s1s = (st[1][0] + st[1][1]) + (st[1][2] + st[1][3]);
      float s2s = (st[2][0] + st[2][1]) + (st[2][2] + st[2][3]);
      float s3s = (st[3][0] + st[3][1]) + (st[3][2] + st[3][3]);
      float rs = (s0s + s1s) + (s2s + s3s);
      rs += __shfl_xor(rs, 16);
      rs += __shfl_xor(rs, 32);
      l_run += rs;

      asm volatile("s_waitcnt lgkmcnt(0)" ::: "memory");
      __builtin_amdgcn_sched_barrier(0);

      // ---- O^T += V^T · P^T
      bf16x8 pb0 = *(const bf16x8*)(pwb + rb0);
      bf16x8 pb1 = *(const bf16x8*)(pwb + rb1);
      __builtin_amdgcn_s_setprio(1);
#pragma unroll
      for (int dj = 0; dj < 4; ++dj) {
        int d = dj * 16 + ln;
        bf16x8 vb0 = *(const bf16x8*)&Vs[buf][d * 64 + ((kg ^ (d & 7)) * 8)];
        bf16x8 vb1 = *(const bf16x8*)&Vs[buf][d * 64 + (((4 + kg) ^ (d & 7)) * 8)];
        acc_o[dj] = __builtin_amdgcn_mfma_f32_16x16x32_bf16(vb0, pb0, acc_o[dj], 0, 0, 0);
        acc_o[dj] = __builtin_amdgcn_mfma_f32_16x16x32_bf16(vb1, pb1, acc_o[dj], 0, 0, 0);
      }
      __builtin_amdgcn_s_setprio(0);
      __syncthreads();   // drains vmcnt (next-tile stage); all waves done with buf
    }

    // ---- epilogue: O^T[d][q=ln] -> [q][d] via per-wave LDS, coalesced store
    asm volatile("s_waitcnt lgkmcnt(0)" ::: "memory");
    float inv = RCP(l_run);
#pragma unroll
    for (int dj = 0; dj < 4; ++dj) {
      unsigned w0 = cvtpk(acc_o[dj][0] * inv, acc_o[dj][1] * inv);
      unsigned w1 = cvtpk(acc_o[dj][2] * inv, acc_o[dj][3] * inv);
      *(unsigned long long*)(pwb + wb[dj]) =
          (unsigned long long)w0 | ((unsigned long long)w1 << 32);
    }
    asm volatile("s_waitcnt lgkmcnt(0)" ::: "memory");
    __builtin_amdgcn_sched_barrier(0);
    {
      const int orow = lane >> 3, og = lane & 7;
      const int lb = ((og ^ (orow & 7)) << 4);
      u16x8 o0 = *(const u16x8*)(pwb + orow * 128 + lb);
      u16x8 o1 = *(const u16x8*)(pwb + (8 + orow) * 128 + lb);
      *(u16x8*)(O + base + (size_t)(q0 + orow) * ND + og * 8) = o0;
      *(u16x8*)(O + base + (size_t)(q0 + 8 + orow) * ND + og * 8) = o1;
    }
  }
}

// ---------------------------------------------------------------- launcher
extern "C" void kernel_launch(void* const* d_in, const int* in_sizes, int n_in,
                              void* d_out, int out_size, void* d_ws, size_t ws_size,
                              hipStream_t stream) {
  const float* x  = (const float*)d_in[0];
  const int*   tp = (const int*)d_in[1];
  const float* Wq = (const float*)d_in[2];
  const float* Wk = (const float*)d_in[3];
  const float* Wv = (const float*)d_in[4];
  const float* Wo = (const float*)d_in[5];
  float* out = (float*)d_out;

  const size_t MD2 = (size_t)NM * ND * 2;  // 16 MiB
  const size_t WW2 = (size_t)ND * ND * 2;  //  2 MiB
  char* w = (char*)d_ws;
  unsigned short* xb  = (unsigned short*)w; w += MD2;
  unsigned short* Qt  = (unsigned short*)w; w += MD2;
  unsigned short* Kt  = (unsigned short*)w; w += MD2;
  unsigned short* Vt  = (unsigned short*)w; w += MD2;
  unsigned short* Wqb = (unsigned short*)w; w += WW2;
  unsigned short* Wkb = (unsigned short*)w; w += WW2;
  unsigned short* Wvb = (unsigned short*)w; w += WW2;
  unsigned short* Wob = (unsigned short*)w; w += WW2;
  unsigned short* Vt2 = xb;  // alias: xb dead after gemm_qkv
  unsigned short* Ot  = Vt;  // alias: Vt dead after transpose_v (attn reads Vt2)

  cast_bf16<<<dim3(8192), 256, 0, stream>>>(x, xb, NM * ND / 4);
  cast_w4<<<dim3(1024, 4), 256, 0, stream>>>(Wq, Wk, Wv, Wo, Wqb, Wkb, Wvb, Wob);
  gemm_qkv<<<dim3(8, 64, 3), 256, 0, stream>>>(xb, Wqb, Wkb, Wvb, tp, Qt, Kt, Vt);
  transpose_v<<<dim3(32, 64), 256, 0, stream>>>(Vt, Vt2);
  attn_kernel<<<dim3(16, 64), 256, 0, stream>>>(Qt, Kt, Vt2, Ot);
  gemm_out<<<dim3(8, 64), 256, 0, stream>>>(Ot, Wob, out);
}

// Round 4
// 197.621 us; speedup vs baseline: 1.9908x; 1.1775x over previous
//
#include <hip/hip_runtime.h>
#include <stdint.h>

#define NB 4
#define NS 2048
#define ND 1024
#define NH 16
#define NM 8192   // NB*NS

typedef __attribute__((ext_vector_type(4))) float          f32x4;
typedef __attribute__((ext_vector_type(8))) __bf16         bf16x8;
typedef __attribute__((ext_vector_type(8))) unsigned short u16x8;
typedef __attribute__((ext_vector_type(4))) unsigned short u16x4;

static __device__ __forceinline__ unsigned short f2bf(float f) {
  unsigned u = __builtin_bit_cast(unsigned, f);
  return (unsigned short)((u + 0x7fffu + ((u >> 16) & 1u)) >> 16);
}

#if __has_builtin(__builtin_amdgcn_exp2f)
#define EX2(x) __builtin_amdgcn_exp2f(x)
#else
#define EX2(x) __expf((x) * 0.69314718056f)
#endif
#if __has_builtin(__builtin_amdgcn_rcpf)
#define RCP(x) __builtin_amdgcn_rcpf(x)
#else
#define RCP(x) (1.0f / (x))
#endif

static __device__ __forceinline__ unsigned cvtpk(float lo, float hi) {
  unsigned r;
  asm("v_cvt_pk_bf16_f32 %0, %1, %2" : "=v"(r) : "v"(lo), "v"(hi));
  return r;
}

static __device__ __forceinline__ void gld_lds16(const void* g, void* l) {
  __builtin_amdgcn_global_load_lds((const __attribute__((address_space(1))) void*)g,
                                   (__attribute__((address_space(3))) void*)l, 16, 0, 0);
}

// ---------------------------------------------------------------- cast f32->bf16
__global__ __launch_bounds__(256) void cast_bf16(const float* __restrict__ in,
                                                 unsigned short* __restrict__ out,
                                                 int n4) {
  int i = blockIdx.x * 256 + threadIdx.x;
  if (i >= n4) return;
  f32x4 v = ((const f32x4*)in)[i];
  u16x4 o;
#pragma unroll
  for (int e = 0; e < 4; ++e) o[e] = f2bf(v[e]);
  ((u16x4*)out)[i] = o;
}

__global__ __launch_bounds__(256) void cast_w4(
    const float* __restrict__ a, const float* __restrict__ b,
    const float* __restrict__ c, const float* __restrict__ d,
    unsigned short* __restrict__ oa, unsigned short* __restrict__ ob,
    unsigned short* __restrict__ oc, unsigned short* __restrict__ od) {
  int z = blockIdx.y;
  const float* in = (z == 0) ? a : (z == 1) ? b : (z == 2) ? c : d;
  unsigned short* out = (z == 0) ? oa : (z == 1) ? ob : (z == 2) ? oc : od;
  int i = blockIdx.x * 256 + threadIdx.x;
  f32x4 v = ((const f32x4*)in)[i];
  u16x4 o;
#pragma unroll
  for (int e = 0; e < 4; ++e) o[e] = f2bf(v[e]);
  ((u16x4*)out)[i] = o;
}

// ---------------------------------------------------------------- fused QKV GEMM
// Tile 128m x 64n per WG, all three weight matrices at once (A staged once).
// 4 waves (2m x 2n), BK=32, double-buffered 2-phase. Epilogues:
//   z=0,1 (Q,K): fused interleaved RoPE -> row-major [m][n]
//   z=2   (V):   in-LDS transpose -> Vt2 [bh][d][s]
__global__ __launch_bounds__(256, 3) void gemm_qkv_fused(
    const unsigned short* __restrict__ A,      // xb [8192][1024]
    const unsigned short* __restrict__ Wqkv,   // Wq,Wk,Wv contiguous [1024][1024]
    const int* __restrict__ tp,
    unsigned short* __restrict__ QKt,          // Qt,Kt contiguous [8192][1024]
    unsigned short* __restrict__ Vt2)          // [64 bh][64 d][2048 s]
{
  union SMem {
    struct { unsigned short As[2][128 * 32]; unsigned short Bs[2][3][64 * 32]; } g;
    unsigned short Tt[64][136];  // V-transpose scratch (pad 136: 2-way banks)
  };
  __shared__ SMem sm;

  const int tid  = threadIdx.x;
  const int wid  = tid >> 6, lane = tid & 63;
  const int ln   = lane & 15, kg = lane >> 4;
  const int wr   = wid >> 1,  wc = wid & 1;
  const int m0   = blockIdx.y * 128, n0 = blockIdx.x * 64;

  // A staging: chunks c = tid, tid+256 -> row r=c>>2, slot s=c&3 (16B)
  const int rA0 = tid >> 2,        sA = tid & 3;
  const int rA1 = (tid + 256) >> 2;
  const int fA0 = (rA0 & 3) ^ ((rA0 >> 2) & 3);
  const int fA1 = (rA1 & 3) ^ ((rA1 >> 2) & 3);
  // B staging: chunk c = tid -> row 0..63
  const int rB = tid >> 2;
  const int fB = (rB & 3) ^ ((rB >> 2) & 3);

  const unsigned short* gA0 = A + (size_t)(m0 + rA0) * ND + ((sA ^ fA0) * 8);
  const unsigned short* gA1 = A + (size_t)(m0 + rA1) * ND + ((sA ^ fA1) * 8);
  const unsigned short* gBq = Wqkv + (size_t)(n0 + rB) * ND + ((sA ^ fB) * 8);
  const unsigned short* gBk = gBq + (size_t)ND * ND;
  const unsigned short* gBv = gBk + (size_t)ND * ND;

  const int ldsA0 = wid * 512;            // elements
  const int ldsA1 = 2048 + wid * 512;
  const int ldsB  = wid * 512;

  const int fql = (ln & 3) ^ ((ln >> 2) & 3);
  int offA[4], offB[2];
#pragma unroll
  for (int i = 0; i < 4; ++i)
    offA[i] = (wr * 64 + i * 16 + ln) * 32 + ((kg ^ fql) * 8);
#pragma unroll
  for (int j = 0; j < 2; ++j)
    offB[j] = (wc * 32 + j * 16 + ln) * 32 + ((kg ^ fql) * 8);

  f32x4 acc[3][4][2];
#pragma unroll
  for (int z = 0; z < 3; ++z)
#pragma unroll
    for (int i = 0; i < 4; ++i)
#pragma unroll
      for (int j = 0; j < 2; ++j) acc[z][i][j] = (f32x4){0.f, 0.f, 0.f, 0.f};

  // prologue: stage k-tile 0 into buf 0
  gld_lds16(gA0, &sm.g.As[0][ldsA0]);
  gld_lds16(gA1, &sm.g.As[0][ldsA1]);
  gld_lds16(gBq, &sm.g.Bs[0][0][ldsB]);
  gld_lds16(gBk, &sm.g.Bs[0][1][ldsB]);
  gld_lds16(gBv, &sm.g.Bs[0][2][ldsB]);
  gA0 += 32; gA1 += 32; gBq += 32; gBk += 32; gBv += 32;
  __syncthreads();

  for (int t = 0; t < 32; ++t) {
    const int buf = t & 1;
    if (t < 31) {
      const int nb = buf ^ 1;
      gld_lds16(gA0, &sm.g.As[nb][ldsA0]);
      gld_lds16(gA1, &sm.g.As[nb][ldsA1]);
      gld_lds16(gBq, &sm.g.Bs[nb][0][ldsB]);
      gld_lds16(gBk, &sm.g.Bs[nb][1][ldsB]);
      gld_lds16(gBv, &sm.g.Bs[nb][2][ldsB]);
      gA0 += 32; gA1 += 32; gBq += 32; gBk += 32; gBv += 32;
    }
    bf16x8 af[4];
#pragma unroll
    for (int i = 0; i < 4; ++i) af[i] = *(const bf16x8*)&sm.g.As[buf][offA[i]];
#pragma unroll
    for (int z = 0; z < 3; ++z) {
      bf16x8 b0 = *(const bf16x8*)&sm.g.Bs[buf][z][offB[0]];
      bf16x8 b1 = *(const bf16x8*)&sm.g.Bs[buf][z][offB[1]];
#pragma unroll
      for (int i = 0; i < 4; ++i) {
        acc[z][i][0] = __builtin_amdgcn_mfma_f32_16x16x32_bf16(af[i], b0, acc[z][i][0], 0, 0, 0);
        acc[z][i][1] = __builtin_amdgcn_mfma_f32_16x16x32_bf16(af[i], b1, acc[z][i][1], 0, 0, 0);
      }
    }
    __syncthreads();
  }

  // ---- V epilogue: transpose in LDS, write Vt2[bh][d][s] coalesced
#pragma unroll
  for (int i = 0; i < 4; ++i)
#pragma unroll
    for (int r = 0; r < 4; ++r) {
      int ml = wr * 64 + i * 16 + kg * 4 + r;
#pragma unroll
      for (int j = 0; j < 2; ++j) {
        int nl = wc * 32 + j * 16 + ln;
        sm.Tt[nl][ml] = f2bf(acc[2][i][j][r]);
      }
    }
  __syncthreads();
  {
    const int b = m0 >> 11, s0 = m0 & 2047;
    unsigned short* vdst = Vt2 + ((size_t)(b * 16 + blockIdx.x) * 64) * NS + s0;
#pragma unroll
    for (int k = 0; k < 4; ++k) {
      int q = tid + k * 256;          // 1024 chunks of 16B
      int row = q >> 4, off = q & 15;
      u16x8 v = *(const u16x8*)&sm.Tt[row][off * 8];
      *(u16x8*)(vdst + (size_t)row * NS + off * 8) = v;
    }
  }

  // ---- Q,K epilogue with fused RoPE
#pragma unroll
  for (int z = 0; z < 2; ++z) {
    unsigned short* C = QKt + (size_t)z * NM * ND;
#pragma unroll
    for (int i = 0; i < 4; ++i)
#pragma unroll
      for (int r = 0; r < 4; ++r) {
        int m = m0 + wr * 64 + i * 16 + kg * 4 + r;
        float pos = (float)tp[m];
#pragma unroll
        for (int j = 0; j < 2; ++j) {
          int n = n0 + wc * 32 + j * 16 + ln;
          float v  = acc[z][i][j][r];
          float pv = __shfl_xor(v, 1);
          int   ip   = (n & 63) >> 1;
          float invf = __expf(-0.28782313662425572f * (float)ip);
          float ang  = pos * invf;
          float sn, cs;
          __sincosf(ang, &sn, &cs);
          float outv = (n & 1) ? (pv * sn + v * cs) : (v * cs - pv * sn);
          C[(size_t)m * ND + n] = f2bf(outv);
        }
      }
  }
}

// ---------------------------------------------------------------- output GEMM
// C[m,n] = sum_k A[m,k]*Bw[n,k], f32 out. 128x128 tile, dbuf 2-phase.
__global__ __launch_bounds__(256, 3) void gemm_out(
    const unsigned short* __restrict__ A,
    const unsigned short* __restrict__ Bw,
    float* __restrict__ C)
{
  __shared__ unsigned short As[2][128 * 32];
  __shared__ unsigned short Bs[2][128 * 32];

  const int tid  = threadIdx.x;
  const int wid  = tid >> 6, lane = tid & 63;
  const int ln   = lane & 15, kg = lane >> 4;
  const int wr   = wid >> 1,  wc = wid & 1;
  const int m0   = blockIdx.y * 128, n0 = blockIdx.x * 128;

  const int r0 = tid >> 2,        s0 = tid & 3;
  const int r1 = (tid + 256) >> 2;
  const int f0 = (r0 & 3) ^ ((r0 >> 2) & 3);
  const int f1 = (r1 & 3) ^ ((r1 >> 2) & 3);

  const unsigned short* gA0 = A  + (size_t)(m0 + r0) * ND + ((s0 ^ f0) * 8);
  const unsigned short* gA1 = A  + (size_t)(m0 + r1) * ND + ((s0 ^ f1) * 8);
  const unsigned short* gB0 = Bw + (size_t)(n0 + r0) * ND + ((s0 ^ f0) * 8);
  const unsigned short* gB1 = Bw + (size_t)(n0 + r1) * ND + ((s0 ^ f1) * 8);

  const int ldsO0 = wid * 512, ldsO1 = 2048 + wid * 512;

  const int fql = (ln & 3) ^ ((ln >> 2) & 3);
  int offA[4], offB[4];
#pragma unroll
  for (int i = 0; i < 4; ++i) {
    offA[i] = (wr * 64 + i * 16 + ln) * 32 + ((kg ^ fql) * 8);
    offB[i] = (wc * 64 + i * 16 + ln) * 32 + ((kg ^ fql) * 8);
  }

  f32x4 acc[4][4];
#pragma unroll
  for (int i = 0; i < 4; ++i)
#pragma unroll
    for (int j = 0; j < 4; ++j) acc[i][j] = (f32x4){0.f, 0.f, 0.f, 0.f};

  gld_lds16(gA0, &As[0][ldsO0]);
  gld_lds16(gA1, &As[0][ldsO1]);
  gld_lds16(gB0, &Bs[0][ldsO0]);
  gld_lds16(gB1, &Bs[0][ldsO1]);
  gA0 += 32; gA1 += 32; gB0 += 32; gB1 += 32;
  __syncthreads();

  for (int t = 0; t < 32; ++t) {
    const int buf = t & 1;
    if (t < 31) {
      const int nb = buf ^ 1;
      gld_lds16(gA0, &As[nb][ldsO0]);
      gld_lds16(gA1, &As[nb][ldsO1]);
      gld_lds16(gB0, &Bs[nb][ldsO0]);
      gld_lds16(gB1, &Bs[nb][ldsO1]);
      gA0 += 32; gA1 += 32; gB0 += 32; gB1 += 32;
    }
    bf16x8 af[4], bfr[4];
#pragma unroll
    for (int i = 0; i < 4; ++i) af[i] = *(const bf16x8*)&As[buf][offA[i]];
#pragma unroll
    for (int j = 0; j < 4; ++j) bfr[j] = *(const bf16x8*)&Bs[buf][offB[j]];
#pragma unroll
    for (int i = 0; i < 4; ++i)
#pragma unroll
      for (int j = 0; j < 4; ++j)
        acc[i][j] = __builtin_amdgcn_mfma_f32_16x16x32_bf16(af[i], bfr[j], acc[i][j], 0, 0, 0);
    __syncthreads();
  }

#pragma unroll
  for (int i = 0; i < 4; ++i)
#pragma unroll
    for (int j = 0; j < 4; ++j)
#pragma unroll
      for (int r = 0; r < 4; ++r) {
        int m = m0 + wr * 64 + i * 16 + kg * 4 + r;
        int n = n0 + wc * 64 + j * 16 + ln;
        C[(size_t)m * ND + n] = acc[i][j][r];
      }
}

// ---------------------------------------------------------------- flash attention
// Swapped-operand layout: S^T = K·Q^T so each lane owns ONE q-row (q = ln).
// grid (16 qb-pairs, 64 bh). 4 waves x 16 q-rows. KV tiles of 64, 2-phase dbuf.
__global__ __launch_bounds__(256, 4) void attn_kernel(
    const unsigned short* __restrict__ Q,
    const unsigned short* __restrict__ K,
    const unsigned short* __restrict__ Vt2,
    unsigned short* __restrict__ O)
{
  __shared__ unsigned short Ks[2][64 * 64];
  __shared__ unsigned short Vs[2][64 * 64];
  __shared__ unsigned long long Pw[4][256];   // per-wave 2KB P/O staging

  const int tid = threadIdx.x;
  const int wid = tid >> 6, lane = tid & 63;
  const int ln  = lane & 15, kg = lane >> 4;
  const int bh  = blockIdx.y;
  const int b   = bh >> 4, h = bh & 15;

  const size_t base  = (size_t)b * NS * ND + (size_t)h * 64;
  const size_t vbase = (size_t)bh * 64 * NS;

  const int cA = tid,      cB = tid + 256;
  const int rA = cA >> 3,  slA = cA & 7;
  const int rB = cB >> 3,  slB = cB & 7;

  const unsigned short* KgA = K + base + (size_t)rA * ND + ((slA ^ (rA & 7)) * 8);
  const unsigned short* KgB = K + base + (size_t)rB * ND + ((slB ^ (rB & 7)) * 8);
  const unsigned short* VgA = Vt2 + vbase + (size_t)rA * NS + ((slA ^ (rA & 7)) * 8);
  const unsigned short* VgB = Vt2 + vbase + (size_t)rB * NS + ((slB ^ (rB & 7)) * 8);

  const int ldsOffA = wid * 512 + lane * 8;
  const int ldsOffB = 2048 + wid * 512 + lane * 8;

  char* pwb = (char*)&Pw[wid][0];
  int wb[4];
#pragma unroll
  for (int j = 0; j < 4; ++j)
    wb[j] = ln * 128 + (((2 * j + (kg >> 1)) ^ (ln & 7)) << 4) + ((kg & 1) << 3);
  const int rb0 = ln * 128 + ((kg ^ (ln & 7)) << 4);
  const int rb1 = ln * 128 + (((4 + kg) ^ (ln & 7)) << 4);

  const float C2 = 0.18033688011111543f;  // 0.125 * log2(e)

  int qbs0 = blockIdx.x, qbs1 = 31 - blockIdx.x;

  for (int pi = 0; pi < 2; ++pi) {
    const int qb = pi ? qbs1 : qbs0;
    const int nt = qb + 1;
    const int q0 = qb * 64 + wid * 16;
    const int qloc = wid * 16 + ln;

    bf16x8 qf[2];
    {
      const unsigned short* qp = Q + base + (size_t)(q0 + ln) * ND + kg * 8;
      qf[0] = *(const bf16x8*)qp;
      qf[1] = *(const bf16x8*)(qp + 32);
    }

    float m_run = -1e30f, l_run = 0.f;
    f32x4 acc_o[4];
#pragma unroll
    for (int dj = 0; dj < 4; ++dj) acc_o[dj] = (f32x4){0.f, 0.f, 0.f, 0.f};

    gld_lds16(KgA, &Ks[0][ldsOffA]);
    gld_lds16(KgB, &Ks[0][ldsOffB]);
    gld_lds16(VgA, &Vs[0][ldsOffA]);
    gld_lds16(VgB, &Vs[0][ldsOffB]);
    __syncthreads();

    for (int t = 0; t < nt; ++t) {
      const int buf = t & 1;
      if (t + 1 < nt) {
        const size_t ko = (size_t)(t + 1) * 64 * ND;
        const int    vo = (t + 1) * 64;
        const int nb = buf ^ 1;
        gld_lds16(KgA + ko, &Ks[nb][ldsOffA]);
        gld_lds16(KgB + ko, &Ks[nb][ldsOffB]);
        gld_lds16(VgA + vo, &Vs[nb][ldsOffA]);
        gld_lds16(VgB + vo, &Vs[nb][ldsOffB]);
      }

      // ---- S^T = K·Q^T : st[j][r] = S^T[kv=16j+4kg+r][q=q0+ln]
      f32x4 st[4];
      __builtin_amdgcn_s_setprio(1);
#pragma unroll
      for (int j = 0; j < 4; ++j) {
        int kvr = j * 16 + ln;
        bf16x8 k0 = *(const bf16x8*)&Ks[buf][kvr * 64 + ((kg ^ (kvr & 7)) * 8)];
        bf16x8 k1 = *(const bf16x8*)&Ks[buf][kvr * 64 + (((4 + kg) ^ (kvr & 7)) * 8)];
        f32x4 z = (f32x4){0.f, 0.f, 0.f, 0.f};
        z = __builtin_amdgcn_mfma_f32_16x16x32_bf16(k0, qf[0], z, 0, 0, 0);
        z = __builtin_amdgcn_mfma_f32_16x16x32_bf16(k1, qf[1], z, 0, 0, 0);
        st[j] = z;
      }
      __builtin_amdgcn_s_setprio(0);

#pragma unroll
      for (int j = 0; j < 4; ++j)
#pragma unroll
        for (int r = 0; r < 4; ++r) st[j][r] *= C2;
      if (t == qb) {
#pragma unroll
        for (int j = 0; j < 4; ++j)
#pragma unroll
          for (int r = 0; r < 4; ++r)
            if (16 * j + 4 * kg + r > qloc) st[j][r] = -1e30f;
      }

      float a0 = fmaxf(fmaxf(st[0][0], st[0][1]), fmaxf(st[0][2], st[0][3]));
      float a1 = fmaxf(fmaxf(st[1][0], st[1][1]), fmaxf(st[1][2], st[1][3]));
      float a2 = fmaxf(fmaxf(st[2][0], st[2][1]), fmaxf(st[2][2], st[2][3]));
      float a3 = fmaxf(fmaxf(st[3][0], st[3][1]), fmaxf(st[3][2], st[3][3]));
      float mx = fmaxf(fmaxf(a0, a1), fmaxf(a2, a3));
      mx = fmaxf(mx, __shfl_xor(mx, 16));
      mx = fmaxf(mx, __shfl_xor(mx, 32));

      if (__any(mx > m_run + 11.0f)) {
        float mnew = fmaxf(m_run, mx);
        float alpha = EX2(m_run - mnew);
        m_run = mnew;
        l_run *= alpha;
#pragma unroll
        for (int dj = 0; dj < 4; ++dj)
#pragma unroll
          for (int r = 0; r < 4; ++r) acc_o[dj][r] *= alpha;
      }

#pragma unroll
      for (int j = 0; j < 4; ++j)
#pragma unroll
        for (int r = 0; r < 4; ++r) st[j][r] = EX2(st[j][r] - m_run);

#pragma unroll
      for (int j = 0; j < 4; ++j) {
        unsigned w0 = cvtpk(st[j][0], st[j][1]);
        unsigned w1 = cvtpk(st[j][2], st[j][3]);
        *(unsigned long long*)(pwb + wb[j]) =
            (unsigned long long)w0 | ((unsigned long long)w1 << 32);
      }

      float s0s = (st[0][0] + st[0][1]) + (st[0][2] + st[0][3]);
      float s1s = (st[1][0] + st[1][1]) + (st[1][2] + st[1][3]);
      float s2s = (st[2][0] + st[2][1]) + (st[2][2] + st[2][3]);
      float s3s = (st[3][0] + st[3][1]) + (st[3][2] + st[3][3]);
      float rs = (s0s + s1s) + (s2s + s3s);
      rs += __shfl_xor(rs, 16);
      rs += __shfl_xor(rs, 32);
      l_run += rs;

      asm volatile("s_waitcnt lgkmcnt(0)" ::: "memory");
      __builtin_amdgcn_sched_barrier(0);

      bf16x8 pb0 = *(const bf16x8*)(pwb + rb0);
      bf16x8 pb1 = *(const bf16x8*)(pwb + rb1);
      __builtin_amdgcn_s_setprio(1);
#pragma unroll
      for (int dj = 0; dj < 4; ++dj) {
        int d = dj * 16 + ln;
        bf16x8 vb0 = *(const bf16x8*)&Vs[buf][d * 64 + ((kg ^ (d & 7)) * 8)];
        bf16x8 vb1 = *(const bf16x8*)&Vs[buf][d * 64 + (((4 + kg) ^ (d & 7)) * 8)];
        acc_o[dj] = __builtin_amdgcn_mfma_f32_16x16x32_bf16(vb0, pb0, acc_o[dj], 0, 0, 0);
        acc_o[dj] = __builtin_amdgcn_mfma_f32_16x16x32_bf16(vb1, pb1, acc_o[dj], 0, 0, 0);
      }
      __builtin_amdgcn_s_setprio(0);
      __syncthreads();
    }

    asm volatile("s_waitcnt lgkmcnt(0)" ::: "memory");
    float inv = RCP(l_run);
#pragma unroll
    for (int dj = 0; dj < 4; ++dj) {
      unsigned w0 = cvtpk(acc_o[dj][0] * inv, acc_o[dj][1] * inv);
      unsigned w1 = cvtpk(acc_o[dj][2] * inv, acc_o[dj][3] * inv);
      *(unsigned long long*)(pwb + wb[dj]) =
          (unsigned long long)w0 | ((unsigned long long)w1 << 32);
    }
    asm volatile("s_waitcnt lgkmcnt(0)" ::: "memory");
    __builtin_amdgcn_sched_barrier(0);
    {
      const int orow = lane >> 3, og = lane & 7;
      const int lb = ((og ^ (orow & 7)) << 4);
      u16x8 o0 = *(const u16x8*)(pwb + orow * 128 + lb);
      u16x8 o1 = *(const u16x8*)(pwb + (8 + orow) * 128 + lb);
      *(u16x8*)(O + base + (size_t)(q0 + orow) * ND + og * 8) = o0;
      *(u16x8*)(O + base + (size_t)(q0 + 8 + orow) * ND + og * 8) = o1;
    }
  }
}

// ---------------------------------------------------------------- launcher
extern "C" void kernel_launch(void* const* d_in, const int* in_sizes, int n_in,
                              void* d_out, int out_size, void* d_ws, size_t ws_size,
                              hipStream_t stream) {
  const float* x  = (const float*)d_in[0];
  const int*   tp = (const int*)d_in[1];
  const float* Wq = (const float*)d_in[2];
  const float* Wk = (const float*)d_in[3];
  const float* Wv = (const float*)d_in[4];
  const float* Wo = (const float*)d_in[5];
  float* out = (float*)d_out;

  const size_t MD2 = (size_t)NM * ND * 2;  // 16 MiB
  const size_t WW2 = (size_t)ND * ND * 2;  //  2 MiB
  char* w = (char*)d_ws;
  unsigned short* xb  = (unsigned short*)w; w += MD2;
  unsigned short* Qt  = (unsigned short*)w; w += MD2;   // Qt,Kt contiguous
  unsigned short* Kt  = (unsigned short*)w; w += MD2;
  unsigned short* Vt2 = (unsigned short*)w; w += MD2;
  unsigned short* Wqb = (unsigned short*)w; w += WW2;   // Wq,Wk,Wv contiguous
  unsigned short* Wkb = (unsigned short*)w; w += WW2;
  unsigned short* Wvb = (unsigned short*)w; w += WW2;
  unsigned short* Wob = (unsigned short*)w; w += WW2;
  unsigned short* Ot  = xb;  // alias: xb dead after gemm_qkv_fused

  cast_bf16<<<dim3(8192), 256, 0, stream>>>(x, xb, NM * ND / 4);
  cast_w4<<<dim3(1024, 4), 256, 0, stream>>>(Wq, Wk, Wv, Wo, Wqb, Wkb, Wvb, Wob);
  gemm_qkv_fused<<<dim3(16, 64), 256, 0, stream>>>(xb, Wqb, tp, Qt, Vt2);
  attn_kernel<<<dim3(16, 64), 256, 0, stream>>>(Qt, Kt, Vt2, Ot);
  gemm_out<<<dim3(8, 64), 256, 0, stream>>>(Ot, Wob, out);
}

// Round 5
// 178.990 us; speedup vs baseline: 2.1980x; 1.1041x over previous
//
#include <hip/hip_runtime.h>
#include <stdint.h>

#define NB 4
#define NS 2048
#define ND 1024
#define NH 16
#define NM 8192   // NB*NS

typedef __attribute__((ext_vector_type(4))) float          f32x4;
typedef __attribute__((ext_vector_type(8))) __bf16         bf16x8;
typedef __attribute__((ext_vector_type(8))) unsigned short u16x8;
typedef __attribute__((ext_vector_type(4))) unsigned short u16x4;

static __device__ __forceinline__ unsigned short f2bf(float f) {
  unsigned u = __builtin_bit_cast(unsigned, f);
  return (unsigned short)((u + 0x7fffu + ((u >> 16) & 1u)) >> 16);
}

#if __has_builtin(__builtin_amdgcn_exp2f)
#define EX2(x) __builtin_amdgcn_exp2f(x)
#else
#define EX2(x) __expf((x) * 0.69314718056f)
#endif
#if __has_builtin(__builtin_amdgcn_rcpf)
#define RCP(x) __builtin_amdgcn_rcpf(x)
#else
#define RCP(x) (1.0f / (x))
#endif

static __device__ __forceinline__ unsigned cvtpk(float lo, float hi) {
  unsigned r;
  asm("v_cvt_pk_bf16_f32 %0, %1, %2" : "=v"(r) : "v"(lo), "v"(hi));
  return r;
}

static __device__ __forceinline__ void gld_lds16(const void* g, void* l) {
  __builtin_amdgcn_global_load_lds((const __attribute__((address_space(1))) void*)g,
                                   (__attribute__((address_space(3))) void*)l, 16, 0, 0);
}

// ---------------------------------------------------------------- cast f32->bf16
__global__ __launch_bounds__(256) void cast_bf16(const float* __restrict__ in,
                                                 unsigned short* __restrict__ out,
                                                 int n4) {
  int i = blockIdx.x * 256 + threadIdx.x;
  if (i >= n4) return;
  f32x4 v = ((const f32x4*)in)[i];
  u16x4 o;
#pragma unroll
  for (int e = 0; e < 4; ++e) o[e] = f2bf(v[e]);
  ((u16x4*)out)[i] = o;
}

__global__ __launch_bounds__(256) void cast_w4(
    const float* __restrict__ a, const float* __restrict__ b,
    const float* __restrict__ c, const float* __restrict__ d,
    unsigned short* __restrict__ oa, unsigned short* __restrict__ ob,
    unsigned short* __restrict__ oc, unsigned short* __restrict__ od) {
  int z = blockIdx.y;
  const float* in = (z == 0) ? a : (z == 1) ? b : (z == 2) ? c : d;
  unsigned short* out = (z == 0) ? oa : (z == 1) ? ob : (z == 2) ? oc : od;
  int i = blockIdx.x * 256 + threadIdx.x;
  f32x4 v = ((const f32x4*)in)[i];
  u16x4 o;
#pragma unroll
  for (int e = 0; e < 4; ++e) o[e] = f2bf(v[e]);
  ((u16x4*)out)[i] = o;
}

// ---------------------------------------------------------------- fused QKV GEMM
// Tile 128m x 64n per WG, all three weight matrices at once (A staged once).
// 4 waves (2m x 2n), BK=32, double-buffered 2-phase. Epilogues:
//   z=0 (Q): fused RoPE, pre-scaled by 0.125*log2(e) (softmax fold)
//   z=1 (K): fused RoPE
//   z=2 (V): in-LDS transpose -> Vt2 [bh][d][s]
__global__ __launch_bounds__(256, 3) void gemm_qkv_fused(
    const unsigned short* __restrict__ A,      // xb [8192][1024]
    const unsigned short* __restrict__ Wqkv,   // Wq,Wk,Wv contiguous [1024][1024]
    const int* __restrict__ tp,
    unsigned short* __restrict__ QKt,          // Qt,Kt contiguous [8192][1024]
    unsigned short* __restrict__ Vt2)          // [64 bh][64 d][2048 s]
{
  union SMem {
    struct { unsigned short As[2][128 * 32]; unsigned short Bs[2][3][64 * 32]; } g;
    unsigned short Tt[64][136];  // V-transpose scratch (pad 136: 2-way banks)
  };
  __shared__ SMem sm;

  const int tid  = threadIdx.x;
  const int wid  = tid >> 6, lane = tid & 63;
  const int ln   = lane & 15, kg = lane >> 4;
  const int wr   = wid >> 1,  wc = wid & 1;
  const int m0   = blockIdx.y * 128, n0 = blockIdx.x * 64;

  const int rA0 = tid >> 2,        sA = tid & 3;
  const int rA1 = (tid + 256) >> 2;
  const int fA0 = (rA0 & 3) ^ ((rA0 >> 2) & 3);
  const int fA1 = (rA1 & 3) ^ ((rA1 >> 2) & 3);
  const int rB = tid >> 2;
  const int fB = (rB & 3) ^ ((rB >> 2) & 3);

  const unsigned short* gA0 = A + (size_t)(m0 + rA0) * ND + ((sA ^ fA0) * 8);
  const unsigned short* gA1 = A + (size_t)(m0 + rA1) * ND + ((sA ^ fA1) * 8);
  const unsigned short* gBq = Wqkv + (size_t)(n0 + rB) * ND + ((sA ^ fB) * 8);
  const unsigned short* gBk = gBq + (size_t)ND * ND;
  const unsigned short* gBv = gBk + (size_t)ND * ND;

  const int ldsA0 = wid * 512;
  const int ldsA1 = 2048 + wid * 512;
  const int ldsB  = wid * 512;

  const int fql = (ln & 3) ^ ((ln >> 2) & 3);
  int offA[4], offB[2];
#pragma unroll
  for (int i = 0; i < 4; ++i)
    offA[i] = (wr * 64 + i * 16 + ln) * 32 + ((kg ^ fql) * 8);
#pragma unroll
  for (int j = 0; j < 2; ++j)
    offB[j] = (wc * 32 + j * 16 + ln) * 32 + ((kg ^ fql) * 8);

  f32x4 acc[3][4][2];
#pragma unroll
  for (int z = 0; z < 3; ++z)
#pragma unroll
    for (int i = 0; i < 4; ++i)
#pragma unroll
      for (int j = 0; j < 2; ++j) acc[z][i][j] = (f32x4){0.f, 0.f, 0.f, 0.f};

  gld_lds16(gA0, &sm.g.As[0][ldsA0]);
  gld_lds16(gA1, &sm.g.As[0][ldsA1]);
  gld_lds16(gBq, &sm.g.Bs[0][0][ldsB]);
  gld_lds16(gBk, &sm.g.Bs[0][1][ldsB]);
  gld_lds16(gBv, &sm.g.Bs[0][2][ldsB]);
  gA0 += 32; gA1 += 32; gBq += 32; gBk += 32; gBv += 32;
  __syncthreads();

  for (int t = 0; t < 32; ++t) {
    const int buf = t & 1;
    if (t < 31) {
      const int nb = buf ^ 1;
      gld_lds16(gA0, &sm.g.As[nb][ldsA0]);
      gld_lds16(gA1, &sm.g.As[nb][ldsA1]);
      gld_lds16(gBq, &sm.g.Bs[nb][0][ldsB]);
      gld_lds16(gBk, &sm.g.Bs[nb][1][ldsB]);
      gld_lds16(gBv, &sm.g.Bs[nb][2][ldsB]);
      gA0 += 32; gA1 += 32; gBq += 32; gBk += 32; gBv += 32;
    }
    bf16x8 af[4];
#pragma unroll
    for (int i = 0; i < 4; ++i) af[i] = *(const bf16x8*)&sm.g.As[buf][offA[i]];
#pragma unroll
    for (int z = 0; z < 3; ++z) {
      bf16x8 b0 = *(const bf16x8*)&sm.g.Bs[buf][z][offB[0]];
      bf16x8 b1 = *(const bf16x8*)&sm.g.Bs[buf][z][offB[1]];
#pragma unroll
      for (int i = 0; i < 4; ++i) {
        acc[z][i][0] = __builtin_amdgcn_mfma_f32_16x16x32_bf16(af[i], b0, acc[z][i][0], 0, 0, 0);
        acc[z][i][1] = __builtin_amdgcn_mfma_f32_16x16x32_bf16(af[i], b1, acc[z][i][1], 0, 0, 0);
      }
    }
    __syncthreads();
  }

  // ---- V epilogue: transpose in LDS, write Vt2[bh][d][s] coalesced
#pragma unroll
  for (int i = 0; i < 4; ++i)
#pragma unroll
    for (int r = 0; r < 4; ++r) {
      int ml = wr * 64 + i * 16 + kg * 4 + r;
#pragma unroll
      for (int j = 0; j < 2; ++j) {
        int nl = wc * 32 + j * 16 + ln;
        sm.Tt[nl][ml] = f2bf(acc[2][i][j][r]);
      }
    }
  __syncthreads();
  {
    const int b = m0 >> 11, s0 = m0 & 2047;
    unsigned short* vdst = Vt2 + ((size_t)(b * 16 + blockIdx.x) * 64) * NS + s0;
#pragma unroll
    for (int k = 0; k < 4; ++k) {
      int q = tid + k * 256;
      int row = q >> 4, off = q & 15;
      u16x8 v = *(const u16x8*)&sm.Tt[row][off * 8];
      *(u16x8*)(vdst + (size_t)row * NS + off * 8) = v;
    }
  }

  // ---- Q,K epilogue with fused RoPE (Q pre-scaled by 0.125*log2e)
#pragma unroll
  for (int z = 0; z < 2; ++z) {
    unsigned short* C = QKt + (size_t)z * NM * ND;
    const float sc = (z == 0) ? 0.18033688011111543f : 1.0f;
#pragma unroll
    for (int i = 0; i < 4; ++i)
#pragma unroll
      for (int r = 0; r < 4; ++r) {
        int m = m0 + wr * 64 + i * 16 + kg * 4 + r;
        float pos = (float)tp[m];
#pragma unroll
        for (int j = 0; j < 2; ++j) {
          int n = n0 + wc * 32 + j * 16 + ln;
          float v  = acc[z][i][j][r];
          float pv = __shfl_xor(v, 1);
          int   ip   = (n & 63) >> 1;
          float invf = __expf(-0.28782313662425572f * (float)ip);
          float ang  = pos * invf;
          float sn, cs;
          __sincosf(ang, &sn, &cs);
          float outv = (n & 1) ? (pv * sn + v * cs) : (v * cs - pv * sn);
          C[(size_t)m * ND + n] = f2bf(outv * sc);
        }
      }
  }
}

// ---------------------------------------------------------------- output GEMM
__global__ __launch_bounds__(256, 3) void gemm_out(
    const unsigned short* __restrict__ A,
    const unsigned short* __restrict__ Bw,
    float* __restrict__ C)
{
  __shared__ unsigned short As[2][128 * 32];
  __shared__ unsigned short Bs[2][128 * 32];

  const int tid  = threadIdx.x;
  const int wid  = tid >> 6, lane = tid & 63;
  const int ln   = lane & 15, kg = lane >> 4;
  const int wr   = wid >> 1,  wc = wid & 1;
  const int m0   = blockIdx.y * 128, n0 = blockIdx.x * 128;

  const int r0 = tid >> 2,        s0 = tid & 3;
  const int r1 = (tid + 256) >> 2;
  const int f0 = (r0 & 3) ^ ((r0 >> 2) & 3);
  const int f1 = (r1 & 3) ^ ((r1 >> 2) & 3);

  const unsigned short* gA0 = A  + (size_t)(m0 + r0) * ND + ((s0 ^ f0) * 8);
  const unsigned short* gA1 = A  + (size_t)(m0 + r1) * ND + ((s0 ^ f1) * 8);
  const unsigned short* gB0 = Bw + (size_t)(n0 + r0) * ND + ((s0 ^ f0) * 8);
  const unsigned short* gB1 = Bw + (size_t)(n0 + r1) * ND + ((s0 ^ f1) * 8);

  const int ldsO0 = wid * 512, ldsO1 = 2048 + wid * 512;

  const int fql = (ln & 3) ^ ((ln >> 2) & 3);
  int offA[4], offB[4];
#pragma unroll
  for (int i = 0; i < 4; ++i) {
    offA[i] = (wr * 64 + i * 16 + ln) * 32 + ((kg ^ fql) * 8);
    offB[i] = (wc * 64 + i * 16 + ln) * 32 + ((kg ^ fql) * 8);
  }

  f32x4 acc[4][4];
#pragma unroll
  for (int i = 0; i < 4; ++i)
#pragma unroll
    for (int j = 0; j < 4; ++j) acc[i][j] = (f32x4){0.f, 0.f, 0.f, 0.f};

  gld_lds16(gA0, &As[0][ldsO0]);
  gld_lds16(gA1, &As[0][ldsO1]);
  gld_lds16(gB0, &Bs[0][ldsO0]);
  gld_lds16(gB1, &Bs[0][ldsO1]);
  gA0 += 32; gA1 += 32; gB0 += 32; gB1 += 32;
  __syncthreads();

  for (int t = 0; t < 32; ++t) {
    const int buf = t & 1;
    if (t < 31) {
      const int nb = buf ^ 1;
      gld_lds16(gA0, &As[nb][ldsO0]);
      gld_lds16(gA1, &As[nb][ldsO1]);
      gld_lds16(gB0, &Bs[nb][ldsO0]);
      gld_lds16(gB1, &Bs[nb][ldsO1]);
      gA0 += 32; gA1 += 32; gB0 += 32; gB1 += 32;
    }
    bf16x8 af[4], bfr[4];
#pragma unroll
    for (int i = 0; i < 4; ++i) af[i] = *(const bf16x8*)&As[buf][offA[i]];
#pragma unroll
    for (int j = 0; j < 4; ++j) bfr[j] = *(const bf16x8*)&Bs[buf][offB[j]];
#pragma unroll
    for (int i = 0; i < 4; ++i)
#pragma unroll
      for (int j = 0; j < 4; ++j)
        acc[i][j] = __builtin_amdgcn_mfma_f32_16x16x32_bf16(af[i], bfr[j], acc[i][j], 0, 0, 0);
    __syncthreads();
  }

#pragma unroll
  for (int i = 0; i < 4; ++i)
#pragma unroll
    for (int j = 0; j < 4; ++j)
#pragma unroll
      for (int r = 0; r < 4; ++r) {
        int m = m0 + wr * 64 + i * 16 + kg * 4 + r;
        int n = n0 + wc * 64 + j * 16 + ln;
        C[(size_t)m * ND + n] = acc[i][j][r];
      }
}

// ---------------------------------------------------------------- flash attention
// Swapped-operand layout: S^T = K·Q^T so each lane owns ONE q-row (q = ln).
// 1D grid of 1024 WGs, XCD-grouped: XCD j (= flat&7) owns bh ≡ j (mod 8), so
// each XCD's 8 bh x 512KB K/V = 4MB stays L2-resident. 4 waves x 16 q-rows.
// KV tiles of 64, 2-phase dbuf. Q is pre-scaled by 0.125*log2e (exp2 domain).
__global__ __launch_bounds__(256, 4) void attn_kernel(
    const unsigned short* __restrict__ Q,
    const unsigned short* __restrict__ K,
    const unsigned short* __restrict__ Vt2,
    unsigned short* __restrict__ O)
{
  __shared__ unsigned short Ks[2][64 * 64];
  __shared__ unsigned short Vs[2][64 * 64];
  __shared__ unsigned long long Pw[4][256];   // per-wave 2KB P/O staging

  const int tid = threadIdx.x;
  const int wid = tid >> 6, lane = tid & 63;
  const int ln  = lane & 15, kg = lane >> 4;

  const int flat = blockIdx.x;
  const int xcd  = flat & 7, g = flat >> 3;
  const int bh   = xcd + ((g >> 4) << 3);     // bh % 8 == xcd
  const int xq   = g & 15;
  const int b    = bh >> 4, h = bh & 15;

  const size_t base  = (size_t)b * NS * ND + (size_t)h * 64;
  const size_t vbase = (size_t)bh * 64 * NS;

  const int cA = tid,      cB = tid + 256;
  const int rA = cA >> 3,  slA = cA & 7;
  const int rB = cB >> 3,  slB = cB & 7;

  const unsigned short* KgA = K + base + (size_t)rA * ND + ((slA ^ (rA & 7)) * 8);
  const unsigned short* KgB = K + base + (size_t)rB * ND + ((slB ^ (rB & 7)) * 8);
  const unsigned short* VgA = Vt2 + vbase + (size_t)rA * NS + ((slA ^ (rA & 7)) * 8);
  const unsigned short* VgB = Vt2 + vbase + (size_t)rB * NS + ((slB ^ (rB & 7)) * 8);

  const int ldsOffA = wid * 512 + lane * 8;
  const int ldsOffB = 2048 + wid * 512 + lane * 8;

  char* pwb = (char*)&Pw[wid][0];
  int wb[4];
#pragma unroll
  for (int j = 0; j < 4; ++j)
    wb[j] = ln * 128 + (((2 * j + (kg >> 1)) ^ (ln & 7)) << 4) + ((kg & 1) << 3);
  const int rb0 = ln * 128 + ((kg ^ (ln & 7)) << 4);
  const int rb1 = ln * 128 + (((4 + kg) ^ (ln & 7)) << 4);

  int qbs0 = xq, qbs1 = 31 - xq;

  for (int pi = 0; pi < 2; ++pi) {
    const int qb = pi ? qbs1 : qbs0;
    const int nt = qb + 1;
    const int q0 = qb * 64 + wid * 16;
    const int qloc = wid * 16 + ln;

    bf16x8 qf[2];
    {
      const unsigned short* qp = Q + base + (size_t)(q0 + ln) * ND + kg * 8;
      qf[0] = *(const bf16x8*)qp;
      qf[1] = *(const bf16x8*)(qp + 32);
    }

    float m_run = -1e30f, l_run = 0.f;
    f32x4 acc_o[4];
#pragma unroll
    for (int dj = 0; dj < 4; ++dj) acc_o[dj] = (f32x4){0.f, 0.f, 0.f, 0.f};

    gld_lds16(KgA, &Ks[0][ldsOffA]);
    gld_lds16(KgB, &Ks[0][ldsOffB]);
    gld_lds16(VgA, &Vs[0][ldsOffA]);
    gld_lds16(VgB, &Vs[0][ldsOffB]);
    __syncthreads();

    for (int t = 0; t < nt; ++t) {
      const int buf = t & 1;
      if (t + 1 < nt) {
        const size_t ko = (size_t)(t + 1) * 64 * ND;
        const int    vo = (t + 1) * 64;
        const int nb = buf ^ 1;
        gld_lds16(KgA + ko, &Ks[nb][ldsOffA]);
        gld_lds16(KgB + ko, &Ks[nb][ldsOffB]);
        gld_lds16(VgA + vo, &Vs[nb][ldsOffA]);
        gld_lds16(VgB + vo, &Vs[nb][ldsOffB]);
      }

      // ---- S^T = K·Q^T : st[j][r] = S^T[kv=16j+4kg+r][q=q0+ln] (exp2 domain)
      f32x4 st[4];
      __builtin_amdgcn_s_setprio(1);
#pragma unroll
      for (int j = 0; j < 4; ++j) {
        int kvr = j * 16 + ln;
        bf16x8 k0 = *(const bf16x8*)&Ks[buf][kvr * 64 + ((kg ^ (kvr & 7)) * 8)];
        bf16x8 k1 = *(const bf16x8*)&Ks[buf][kvr * 64 + (((4 + kg) ^ (kvr & 7)) * 8)];
        f32x4 z = (f32x4){0.f, 0.f, 0.f, 0.f};
        z = __builtin_amdgcn_mfma_f32_16x16x32_bf16(k0, qf[0], z, 0, 0, 0);
        z = __builtin_amdgcn_mfma_f32_16x16x32_bf16(k1, qf[1], z, 0, 0, 0);
        st[j] = z;
      }
      __builtin_amdgcn_s_setprio(0);

      if (t == qb) {
#pragma unroll
        for (int j = 0; j < 4; ++j)
#pragma unroll
          for (int r = 0; r < 4; ++r)
            if (16 * j + 4 * kg + r > qloc) st[j][r] = -1e30f;
      }

      float a0 = fmaxf(fmaxf(st[0][0], st[0][1]), fmaxf(st[0][2], st[0][3]));
      float a1 = fmaxf(fmaxf(st[1][0], st[1][1]), fmaxf(st[1][2], st[1][3]));
      float a2 = fmaxf(fmaxf(st[2][0], st[2][1]), fmaxf(st[2][2], st[2][3]));
      float a3 = fmaxf(fmaxf(st[3][0], st[3][1]), fmaxf(st[3][2], st[3][3]));
      float mx = fmaxf(fmaxf(a0, a1), fmaxf(a2, a3));
      mx = fmaxf(mx, __shfl_xor(mx, 16));
      mx = fmaxf(mx, __shfl_xor(mx, 32));

      if (__any(mx > m_run + 11.0f)) {
        float mnew = fmaxf(m_run, mx);
        float alpha = EX2(m_run - mnew);
        m_run = mnew;
        l_run *= alpha;
#pragma unroll
        for (int dj = 0; dj < 4; ++dj)
#pragma unroll
          for (int r = 0; r < 4; ++r) acc_o[dj][r] *= alpha;
      }

#pragma unroll
      for (int j = 0; j < 4; ++j)
#pragma unroll
        for (int r = 0; r < 4; ++r) st[j][r] = EX2(st[j][r] - m_run);

#pragma unroll
      for (int j = 0; j < 4; ++j) {
        unsigned w0 = cvtpk(st[j][0], st[j][1]);
        unsigned w1 = cvtpk(st[j][2], st[j][3]);
        *(unsigned long long*)(pwb + wb[j]) =
            (unsigned long long)w0 | ((unsigned long long)w1 << 32);
      }

      float s0s = (st[0][0] + st[0][1]) + (st[0][2] + st[0][3]);
      float s1s = (st[1][0] + st[1][1]) + (st[1][2] + st[1][3]);
      float s2s = (st[2][0] + st[2][1]) + (st[2][2] + st[2][3]);
      float s3s = (st[3][0] + st[3][1]) + (st[3][2] + st[3][3]);
      float rs = (s0s + s1s) + (s2s + s3s);
      rs += __shfl_xor(rs, 16);
      rs += __shfl_xor(rs, 32);
      l_run += rs;

      asm volatile("s_waitcnt lgkmcnt(0)" ::: "memory");
      __builtin_amdgcn_sched_barrier(0);

      bf16x8 pb0 = *(const bf16x8*)(pwb + rb0);
      bf16x8 pb1 = *(const bf16x8*)(pwb + rb1);
      __builtin_amdgcn_s_setprio(1);
#pragma unroll
      for (int dj = 0; dj < 4; ++dj) {
        int d = dj * 16 + ln;
        bf16x8 vb0 = *(const bf16x8*)&Vs[buf][d * 64 + ((kg ^ (d & 7)) * 8)];
        bf16x8 vb1 = *(const bf16x8*)&Vs[buf][d * 64 + (((4 + kg) ^ (d & 7)) * 8)];
        acc_o[dj] = __builtin_amdgcn_mfma_f32_16x16x32_bf16(vb0, pb0, acc_o[dj], 0, 0, 0);
        acc_o[dj] = __builtin_amdgcn_mfma_f32_16x16x32_bf16(vb1, pb1, acc_o[dj], 0, 0, 0);
      }
      __builtin_amdgcn_s_setprio(0);
      __syncthreads();
    }

    asm volatile("s_waitcnt lgkmcnt(0)" ::: "memory");
    float inv = RCP(l_run);
#pragma unroll
    for (int dj = 0; dj < 4; ++dj) {
      unsigned w0 = cvtpk(acc_o[dj][0] * inv, acc_o[dj][1] * inv);
      unsigned w1 = cvtpk(acc_o[dj][2] * inv, acc_o[dj][3] * inv);
      *(unsigned long long*)(pwb + wb[dj]) =
          (unsigned long long)w0 | ((unsigned long long)w1 << 32);
    }
    asm volatile("s_waitcnt lgkmcnt(0)" ::: "memory");
    __builtin_amdgcn_sched_barrier(0);
    {
      const int orow = lane >> 3, og = lane & 7;
      const int lb = ((og ^ (orow & 7)) << 4);
      u16x8 o0 = *(const u16x8*)(pwb + orow * 128 + lb);
      u16x8 o1 = *(const u16x8*)(pwb + (8 + orow) * 128 + lb);
      *(u16x8*)(O + base + (size_t)(q0 + orow) * ND + og * 8) = o0;
      *(u16x8*)(O + base + (size_t)(q0 + 8 + orow) * ND + og * 8) = o1;
    }
  }
}

// ---------------------------------------------------------------- launcher
extern "C" void kernel_launch(void* const* d_in, const int* in_sizes, int n_in,
                              void* d_out, int out_size, void* d_ws, size_t ws_size,
                              hipStream_t stream) {
  const float* x  = (const float*)d_in[0];
  const int*   tp = (const int*)d_in[1];
  const float* Wq = (const float*)d_in[2];
  const float* Wk = (const float*)d_in[3];
  const float* Wv = (const float*)d_in[4];
  const float* Wo = (const float*)d_in[5];
  float* out = (float*)d_out;

  const size_t MD2 = (size_t)NM * ND * 2;  // 16 MiB
  const size_t WW2 = (size_t)ND * ND * 2;  //  2 MiB
  char* w = (char*)d_ws;
  unsigned short* xb  = (unsigned short*)w; w += MD2;
  unsigned short* Qt  = (unsigned short*)w; w += MD2;   // Qt,Kt contiguous
  unsigned short* Kt  = (unsigned short*)w; w += MD2;
  unsigned short* Vt2 = (unsigned short*)w; w += MD2;
  unsigned short* Wqb = (unsigned short*)w; w += WW2;   // Wq,Wk,Wv contiguous
  unsigned short* Wkb = (unsigned short*)w; w += WW2;
  unsigned short* Wvb = (unsigned short*)w; w += WW2;
  unsigned short* Wob = (unsigned short*)w; w += WW2;
  unsigned short* Ot  = xb;  // alias: xb dead after gemm_qkv_fused

  cast_bf16<<<dim3(8192), 256, 0, stream>>>(x, xb, NM * ND / 4);
  cast_w4<<<dim3(1024, 4), 256, 0, stream>>>(Wq, Wk, Wv, Wo, Wqb, Wkb, Wvb, Wob);
  gemm_qkv_fused<<<dim3(16, 64), 256, 0, stream>>>(xb, Wqb, tp, Qt, Vt2);
  attn_kernel<<<dim3(1024), 256, 0, stream>>>(Qt, Kt, Vt2, Ot);
  gemm_out<<<dim3(8, 64), 256, 0, stream>>>(Ot, Wob, out);
}

// Round 6
// 173.378 us; speedup vs baseline: 2.2692x; 1.0324x over previous
//
#include <hip/hip_runtime.h>
#include <stdint.h>

#define NB 4
#define NS 2048
#define ND 1024
#define NH 16
#define NM 8192   // NB*NS

typedef __attribute__((ext_vector_type(4))) float          f32x4;
typedef __attribute__((ext_vector_type(8))) __bf16         bf16x8;
typedef __attribute__((ext_vector_type(8))) unsigned short u16x8;
typedef __attribute__((ext_vector_type(4))) unsigned short u16x4;

static __device__ __forceinline__ unsigned short f2bf(float f) {
  unsigned u = __builtin_bit_cast(unsigned, f);
  return (unsigned short)((u + 0x7fffu + ((u >> 16) & 1u)) >> 16);
}

#if __has_builtin(__builtin_amdgcn_exp2f)
#define EX2(x) __builtin_amdgcn_exp2f(x)
#else
#define EX2(x) __expf((x) * 0.69314718056f)
#endif
#if __has_builtin(__builtin_amdgcn_rcpf)
#define RCP(x) __builtin_amdgcn_rcpf(x)
#else
#define RCP(x) (1.0f / (x))
#endif

static __device__ __forceinline__ unsigned cvtpk(float lo, float hi) {
  unsigned r;
  asm("v_cvt_pk_bf16_f32 %0, %1, %2" : "=v"(r) : "v"(lo), "v"(hi));
  return r;
}

static __device__ __forceinline__ void gld_lds16(const void* g, void* l) {
  __builtin_amdgcn_global_load_lds((const __attribute__((address_space(1))) void*)g,
                                   (__attribute__((address_space(3))) void*)l, 16, 0, 0);
}

// ---------------------------------------------------------------- cast f32->bf16
__global__ __launch_bounds__(256) void cast_bf16(const float* __restrict__ in,
                                                 unsigned short* __restrict__ out,
                                                 int n4) {
  int i = blockIdx.x * 256 + threadIdx.x;
  if (i >= n4) return;
  f32x4 v = ((const f32x4*)in)[i];
  u16x4 o;
#pragma unroll
  for (int e = 0; e < 4; ++e) o[e] = f2bf(v[e]);
  ((u16x4*)out)[i] = o;
}

__global__ __launch_bounds__(256) void cast_w4(
    const float* __restrict__ a, const float* __restrict__ b,
    const float* __restrict__ c, const float* __restrict__ d,
    unsigned short* __restrict__ oa, unsigned short* __restrict__ ob,
    unsigned short* __restrict__ oc, unsigned short* __restrict__ od) {
  int z = blockIdx.y;
  const float* in = (z == 0) ? a : (z == 1) ? b : (z == 2) ? c : d;
  unsigned short* out = (z == 0) ? oa : (z == 1) ? ob : (z == 2) ? oc : od;
  int i = blockIdx.x * 256 + threadIdx.x;
  f32x4 v = ((const f32x4*)in)[i];
  u16x4 o;
#pragma unroll
  for (int e = 0; e < 4; ++e) o[e] = f2bf(v[e]);
  ((u16x4*)out)[i] = o;
}

// ---------------------------------------------------------------- fused QKV GEMM
// Tile 128m x 64n per WG, all three weight matrices at once (A staged once).
// 4 waves (2m x 2n), BK=32, double-buffered 2-phase. Epilogues:
//   z=0 (Q): fused RoPE, pre-scaled by 0.125*log2(e) (softmax fold)
//   z=1 (K): fused RoPE
//   z=2 (V): in-LDS transpose -> Vt2 [bh][d][s]
__global__ __launch_bounds__(256, 3) void gemm_qkv_fused(
    const unsigned short* __restrict__ A,      // xb [8192][1024]
    const unsigned short* __restrict__ Wqkv,   // Wq,Wk,Wv contiguous [1024][1024]
    const int* __restrict__ tp,
    unsigned short* __restrict__ QKt,          // Qt,Kt contiguous [8192][1024]
    unsigned short* __restrict__ Vt2)          // [64 bh][64 d][2048 s]
{
  union SMem {
    struct { unsigned short As[2][128 * 32]; unsigned short Bs[2][3][64 * 32]; } g;
    unsigned short Tt[64][136];  // V-transpose scratch (pad 136: 2-way banks)
  };
  __shared__ SMem sm;

  const int tid  = threadIdx.x;
  const int wid  = tid >> 6, lane = tid & 63;
  const int ln   = lane & 15, kg = lane >> 4;
  const int wr   = wid >> 1,  wc = wid & 1;
  const int m0   = blockIdx.y * 128, n0 = blockIdx.x * 64;

  const int rA0 = tid >> 2,        sA = tid & 3;
  const int rA1 = (tid + 256) >> 2;
  const int fA0 = (rA0 & 3) ^ ((rA0 >> 2) & 3);
  const int fA1 = (rA1 & 3) ^ ((rA1 >> 2) & 3);
  const int rB = tid >> 2;
  const int fB = (rB & 3) ^ ((rB >> 2) & 3);

  const unsigned short* gA0 = A + (size_t)(m0 + rA0) * ND + ((sA ^ fA0) * 8);
  const unsigned short* gA1 = A + (size_t)(m0 + rA1) * ND + ((sA ^ fA1) * 8);
  const unsigned short* gBq = Wqkv + (size_t)(n0 + rB) * ND + ((sA ^ fB) * 8);
  const unsigned short* gBk = gBq + (size_t)ND * ND;
  const unsigned short* gBv = gBk + (size_t)ND * ND;

  const int ldsA0 = wid * 512;
  const int ldsA1 = 2048 + wid * 512;
  const int ldsB  = wid * 512;

  const int fql = (ln & 3) ^ ((ln >> 2) & 3);
  int offA[4], offB[2];
#pragma unroll
  for (int i = 0; i < 4; ++i)
    offA[i] = (wr * 64 + i * 16 + ln) * 32 + ((kg ^ fql) * 8);
#pragma unroll
  for (int j = 0; j < 2; ++j)
    offB[j] = (wc * 32 + j * 16 + ln) * 32 + ((kg ^ fql) * 8);

  f32x4 acc[3][4][2];
#pragma unroll
  for (int z = 0; z < 3; ++z)
#pragma unroll
    for (int i = 0; i < 4; ++i)
#pragma unroll
      for (int j = 0; j < 2; ++j) acc[z][i][j] = (f32x4){0.f, 0.f, 0.f, 0.f};

  gld_lds16(gA0, &sm.g.As[0][ldsA0]);
  gld_lds16(gA1, &sm.g.As[0][ldsA1]);
  gld_lds16(gBq, &sm.g.Bs[0][0][ldsB]);
  gld_lds16(gBk, &sm.g.Bs[0][1][ldsB]);
  gld_lds16(gBv, &sm.g.Bs[0][2][ldsB]);
  gA0 += 32; gA1 += 32; gBq += 32; gBk += 32; gBv += 32;
  __syncthreads();

  for (int t = 0; t < 32; ++t) {
    const int buf = t & 1;
    if (t < 31) {
      const int nb = buf ^ 1;
      gld_lds16(gA0, &sm.g.As[nb][ldsA0]);
      gld_lds16(gA1, &sm.g.As[nb][ldsA1]);
      gld_lds16(gBq, &sm.g.Bs[nb][0][ldsB]);
      gld_lds16(gBk, &sm.g.Bs[nb][1][ldsB]);
      gld_lds16(gBv, &sm.g.Bs[nb][2][ldsB]);
      gA0 += 32; gA1 += 32; gBq += 32; gBk += 32; gBv += 32;
    }
    bf16x8 af[4];
#pragma unroll
    for (int i = 0; i < 4; ++i) af[i] = *(const bf16x8*)&sm.g.As[buf][offA[i]];
#pragma unroll
    for (int z = 0; z < 3; ++z) {
      bf16x8 b0 = *(const bf16x8*)&sm.g.Bs[buf][z][offB[0]];
      bf16x8 b1 = *(const bf16x8*)&sm.g.Bs[buf][z][offB[1]];
#pragma unroll
      for (int i = 0; i < 4; ++i) {
        acc[z][i][0] = __builtin_amdgcn_mfma_f32_16x16x32_bf16(af[i], b0, acc[z][i][0], 0, 0, 0);
        acc[z][i][1] = __builtin_amdgcn_mfma_f32_16x16x32_bf16(af[i], b1, acc[z][i][1], 0, 0, 0);
      }
    }
    __syncthreads();
  }

  // ---- V epilogue: transpose in LDS, write Vt2[bh][d][s] coalesced
#pragma unroll
  for (int i = 0; i < 4; ++i)
#pragma unroll
    for (int r = 0; r < 4; ++r) {
      int ml = wr * 64 + i * 16 + kg * 4 + r;
#pragma unroll
      for (int j = 0; j < 2; ++j) {
        int nl = wc * 32 + j * 16 + ln;
        sm.Tt[nl][ml] = f2bf(acc[2][i][j][r]);
      }
    }
  __syncthreads();
  {
    const int b = m0 >> 11, s0 = m0 & 2047;
    unsigned short* vdst = Vt2 + ((size_t)(b * 16 + blockIdx.x) * 64) * NS + s0;
#pragma unroll
    for (int k = 0; k < 4; ++k) {
      int q = tid + k * 256;
      int row = q >> 4, off = q & 15;
      u16x8 v = *(const u16x8*)&sm.Tt[row][off * 8];
      *(u16x8*)(vdst + (size_t)row * NS + off * 8) = v;
    }
  }

  // ---- Q,K epilogue with fused RoPE (Q pre-scaled by 0.125*log2e)
#pragma unroll
  for (int z = 0; z < 2; ++z) {
    unsigned short* C = QKt + (size_t)z * NM * ND;
    const float sc = (z == 0) ? 0.18033688011111543f : 1.0f;
#pragma unroll
    for (int i = 0; i < 4; ++i)
#pragma unroll
      for (int r = 0; r < 4; ++r) {
        int m = m0 + wr * 64 + i * 16 + kg * 4 + r;
        float pos = (float)tp[m];
#pragma unroll
        for (int j = 0; j < 2; ++j) {
          int n = n0 + wc * 32 + j * 16 + ln;
          float v  = acc[z][i][j][r];
          float pv = __shfl_xor(v, 1);
          int   ip   = (n & 63) >> 1;
          float invf = __expf(-0.28782313662425572f * (float)ip);
          float ang  = pos * invf;
          float sn, cs;
          __sincosf(ang, &sn, &cs);
          float outv = (n & 1) ? (pv * sn + v * cs) : (v * cs - pv * sn);
          C[(size_t)m * ND + n] = f2bf(outv * sc);
        }
      }
  }
}

// ---------------------------------------------------------------- output GEMM
__global__ __launch_bounds__(256, 3) void gemm_out(
    const unsigned short* __restrict__ A,
    const unsigned short* __restrict__ Bw,
    float* __restrict__ C)
{
  __shared__ unsigned short As[2][128 * 32];
  __shared__ unsigned short Bs[2][128 * 32];

  const int tid  = threadIdx.x;
  const int wid  = tid >> 6, lane = tid & 63;
  const int ln   = lane & 15, kg = lane >> 4;
  const int wr   = wid >> 1,  wc = wid & 1;
  const int m0   = blockIdx.y * 128, n0 = blockIdx.x * 128;

  const int r0 = tid >> 2,        s0 = tid & 3;
  const int r1 = (tid + 256) >> 2;
  const int f0 = (r0 & 3) ^ ((r0 >> 2) & 3);
  const int f1 = (r1 & 3) ^ ((r1 >> 2) & 3);

  const unsigned short* gA0 = A  + (size_t)(m0 + r0) * ND + ((s0 ^ f0) * 8);
  const unsigned short* gA1 = A  + (size_t)(m0 + r1) * ND + ((s0 ^ f1) * 8);
  const unsigned short* gB0 = Bw + (size_t)(n0 + r0) * ND + ((s0 ^ f0) * 8);
  const unsigned short* gB1 = Bw + (size_t)(n0 + r1) * ND + ((s0 ^ f1) * 8);

  const int ldsO0 = wid * 512, ldsO1 = 2048 + wid * 512;

  const int fql = (ln & 3) ^ ((ln >> 2) & 3);
  int offA[4], offB[4];
#pragma unroll
  for (int i = 0; i < 4; ++i) {
    offA[i] = (wr * 64 + i * 16 + ln) * 32 + ((kg ^ fql) * 8);
    offB[i] = (wc * 64 + i * 16 + ln) * 32 + ((kg ^ fql) * 8);
  }

  f32x4 acc[4][4];
#pragma unroll
  for (int i = 0; i < 4; ++i)
#pragma unroll
    for (int j = 0; j < 4; ++j) acc[i][j] = (f32x4){0.f, 0.f, 0.f, 0.f};

  gld_lds16(gA0, &As[0][ldsO0]);
  gld_lds16(gA1, &As[0][ldsO1]);
  gld_lds16(gB0, &Bs[0][ldsO0]);
  gld_lds16(gB1, &Bs[0][ldsO1]);
  gA0 += 32; gA1 += 32; gB0 += 32; gB1 += 32;
  __syncthreads();

  for (int t = 0; t < 32; ++t) {
    const int buf = t & 1;
    if (t < 31) {
      const int nb = buf ^ 1;
      gld_lds16(gA0, &As[nb][ldsO0]);
      gld_lds16(gA1, &As[nb][ldsO1]);
      gld_lds16(gB0, &Bs[nb][ldsO0]);
      gld_lds16(gB1, &Bs[nb][ldsO1]);
      gA0 += 32; gA1 += 32; gB0 += 32; gB1 += 32;
    }
    bf16x8 af[4], bfr[4];
#pragma unroll
    for (int i = 0; i < 4; ++i) af[i] = *(const bf16x8*)&As[buf][offA[i]];
#pragma unroll
    for (int j = 0; j < 4; ++j) bfr[j] = *(const bf16x8*)&Bs[buf][offB[j]];
#pragma unroll
    for (int i = 0; i < 4; ++i)
#pragma unroll
      for (int j = 0; j < 4; ++j)
        acc[i][j] = __builtin_amdgcn_mfma_f32_16x16x32_bf16(af[i], bfr[j], acc[i][j], 0, 0, 0);
    __syncthreads();
  }

#pragma unroll
  for (int i = 0; i < 4; ++i)
#pragma unroll
    for (int j = 0; j < 4; ++j)
#pragma unroll
      for (int r = 0; r < 4; ++r) {
        int m = m0 + wr * 64 + i * 16 + kg * 4 + r;
        int n = n0 + wc * 64 + j * 16 + ln;
        C[(size_t)m * ND + n] = acc[i][j][r];
      }
}

// ---------------------------------------------------------------- flash attention
// Swapped-operand layout: S^T = K·Q^T so each lane owns ONE q-row (q = ln).
// 8-wave WG (512 thr) over 128 q-rows sharing one K/V staging -> 48KB LDS,
// 3 WGs/CU = 24 waves (75% occupancy cap). 1024 WGs XCD-grouped (bh%8==xcd,
// K/V L2-resident per XCD), qb descending (longest first). KV tiles of 64,
// 2-phase dbuf. Q pre-scaled by 0.125*log2e (exp2 domain).
__global__ __launch_bounds__(512, 6) void attn_kernel(
    const unsigned short* __restrict__ Q,
    const unsigned short* __restrict__ K,
    const unsigned short* __restrict__ Vt2,
    unsigned short* __restrict__ O)
{
  __shared__ unsigned short Ks[2][64 * 64];
  __shared__ unsigned short Vs[2][64 * 64];
  __shared__ unsigned long long Pw[8][256];   // per-wave 2KB P/O staging

  const int tid = threadIdx.x;
  const int wid = tid >> 6, lane = tid & 63;
  const int ln  = lane & 15, kg = lane >> 4;

  const int flat = blockIdx.x;
  const int xcd  = flat & 7, g = flat >> 3;   // g in 0..127
  const int qb   = 15 - (g >> 3);             // 128-row q-block, longest first
  const int bh   = xcd + ((g & 7) << 3);      // bh % 8 == xcd
  const int b    = bh >> 4, h = bh & 15;

  const size_t base  = (size_t)b * NS * ND + (size_t)h * 64;
  const size_t vbase = (size_t)bh * 64 * NS;

  // staging: one 16B chunk per thread per tensor: row = tid>>3, slot = tid&7
  const int rA = tid >> 3, slA = tid & 7;
  const unsigned short* KgA = K + base + (size_t)rA * ND + ((slA ^ (rA & 7)) * 8);
  const unsigned short* VgA = Vt2 + vbase + (size_t)rA * NS + ((slA ^ (rA & 7)) * 8);
  const int ldsOff = tid * 8;

  char* pwb = (char*)&Pw[wid][0];
  int wb[4];
#pragma unroll
  for (int j = 0; j < 4; ++j)
    wb[j] = ln * 128 + (((2 * j + (kg >> 1)) ^ (ln & 7)) << 4) + ((kg & 1) << 3);
  const int rb0 = ln * 128 + ((kg ^ (ln & 7)) << 4);
  const int rb1 = ln * 128 + (((4 + kg) ^ (ln & 7)) << 4);

  const int nt   = 2 * qb + 2;
  const int q0   = qb * 128 + wid * 16;
  const int qrow = wid * 16 + ln;             // q - qb*128 for this lane's row

  bf16x8 qf[2];
  {
    const unsigned short* qp = Q + base + (size_t)(q0 + ln) * ND + kg * 8;
    qf[0] = *(const bf16x8*)qp;
    qf[1] = *(const bf16x8*)(qp + 32);
  }

  float m_run = -1e30f, l_run = 0.f;
  f32x4 acc_o[4];
#pragma unroll
  for (int dj = 0; dj < 4; ++dj) acc_o[dj] = (f32x4){0.f, 0.f, 0.f, 0.f};

  gld_lds16(KgA, &Ks[0][ldsOff]);
  gld_lds16(VgA, &Vs[0][ldsOff]);
  __syncthreads();

  for (int t = 0; t < nt; ++t) {
    const int buf = t & 1;
    if (t + 1 < nt) {
      const size_t ko = (size_t)(t + 1) * 64 * ND;
      const int    vo = (t + 1) * 64;
      const int nb = buf ^ 1;
      gld_lds16(KgA + ko, &Ks[nb][ldsOff]);
      gld_lds16(VgA + vo, &Vs[nb][ldsOff]);
    }

    // ---- S^T = K·Q^T : st[j][r] = S^T[kv=16j+4kg+r][q=q0+ln] (exp2 domain)
    f32x4 st[4];
    __builtin_amdgcn_s_setprio(1);
#pragma unroll
    for (int j = 0; j < 4; ++j) {
      int kvr = j * 16 + ln;
      bf16x8 k0 = *(const bf16x8*)&Ks[buf][kvr * 64 + ((kg ^ (kvr & 7)) * 8)];
      bf16x8 k1 = *(const bf16x8*)&Ks[buf][kvr * 64 + (((4 + kg) ^ (kvr & 7)) * 8)];
      f32x4 z = (f32x4){0.f, 0.f, 0.f, 0.f};
      z = __builtin_amdgcn_mfma_f32_16x16x32_bf16(k0, qf[0], z, 0, 0, 0);
      z = __builtin_amdgcn_mfma_f32_16x16x32_bf16(k1, qf[1], z, 0, 0, 0);
      st[j] = z;
    }
    __builtin_amdgcn_s_setprio(0);

    // ---- causal mask (only the last two tiles touch the diagonal)
    const int trel = t - 2 * qb;
    if (trel >= 0) {
#pragma unroll
      for (int j = 0; j < 4; ++j)
#pragma unroll
        for (int r = 0; r < 4; ++r)
          if (trel * 64 + 16 * j + 4 * kg + r > qrow) st[j][r] = -1e30f;
    }

    float a0 = fmaxf(fmaxf(st[0][0], st[0][1]), fmaxf(st[0][2], st[0][3]));
    float a1 = fmaxf(fmaxf(st[1][0], st[1][1]), fmaxf(st[1][2], st[1][3]));
    float a2 = fmaxf(fmaxf(st[2][0], st[2][1]), fmaxf(st[2][2], st[2][3]));
    float a3 = fmaxf(fmaxf(st[3][0], st[3][1]), fmaxf(st[3][2], st[3][3]));
    float mx = fmaxf(fmaxf(a0, a1), fmaxf(a2, a3));
    mx = fmaxf(mx, __shfl_xor(mx, 16));
    mx = fmaxf(mx, __shfl_xor(mx, 32));

    if (__any(mx > m_run + 11.0f)) {
      float mnew = fmaxf(m_run, mx);
      float alpha = EX2(m_run - mnew);
      m_run = mnew;
      l_run *= alpha;
#pragma unroll
      for (int dj = 0; dj < 4; ++dj)
#pragma unroll
        for (int r = 0; r < 4; ++r) acc_o[dj][r] *= alpha;
    }

#pragma unroll
    for (int j = 0; j < 4; ++j)
#pragma unroll
      for (int r = 0; r < 4; ++r) st[j][r] = EX2(st[j][r] - m_run);

#pragma unroll
    for (int j = 0; j < 4; ++j) {
      unsigned w0 = cvtpk(st[j][0], st[j][1]);
      unsigned w1 = cvtpk(st[j][2], st[j][3]);
      *(unsigned long long*)(pwb + wb[j]) =
          (unsigned long long)w0 | ((unsigned long long)w1 << 32);
    }

    float s0s = (st[0][0] + st[0][1]) + (st[0][2] + st[0][3]);
    float s1s = (st[1][0] + st[1][1]) + (st[1][2] + st[1][3]);
    float s2s = (st[2][0] + st[2][1]) + (st[2][2] + st[2][3]);
    float s3s = (st[3][0] + st[3][1]) + (st[3][2] + st[3][3]);
    float rs = (s0s + s1s) + (s2s + s3s);
    rs += __shfl_xor(rs, 16);
    rs += __shfl_xor(rs, 32);
    l_run += rs;

    asm volatile("s_waitcnt lgkmcnt(0)" ::: "memory");
    __builtin_amdgcn_sched_barrier(0);

    bf16x8 pb0 = *(const bf16x8*)(pwb + rb0);
    bf16x8 pb1 = *(const bf16x8*)(pwb + rb1);
    __builtin_amdgcn_s_setprio(1);
#pragma unroll
    for (int dj = 0; dj < 4; ++dj) {
      int d = dj * 16 + ln;
      bf16x8 vb0 = *(const bf16x8*)&Vs[buf][d * 64 + ((kg ^ (d & 7)) * 8)];
      bf16x8 vb1 = *(const bf16x8*)&Vs[buf][d * 64 + (((4 + kg) ^ (d & 7)) * 8)];
      acc_o[dj] = __builtin_amdgcn_mfma_f32_16x16x32_bf16(vb0, pb0, acc_o[dj], 0, 0, 0);
      acc_o[dj] = __builtin_amdgcn_mfma_f32_16x16x32_bf16(vb1, pb1, acc_o[dj], 0, 0, 0);
    }
    __builtin_amdgcn_s_setprio(0);
    __syncthreads();   // drains vmcnt (next-tile stage); all waves done with buf
  }

  // ---- epilogue: O^T[d][q=ln] -> [q][d] via per-wave LDS, coalesced store
  asm volatile("s_waitcnt lgkmcnt(0)" ::: "memory");
  float inv = RCP(l_run);
#pragma unroll
  for (int dj = 0; dj < 4; ++dj) {
    unsigned w0 = cvtpk(acc_o[dj][0] * inv, acc_o[dj][1] * inv);
    unsigned w1 = cvtpk(acc_o[dj][2] * inv, acc_o[dj][3] * inv);
    *(unsigned long long*)(pwb + wb[dj]) =
        (unsigned long long)w0 | ((unsigned long long)w1 << 32);
  }
  asm volatile("s_waitcnt lgkmcnt(0)" ::: "memory");
  __builtin_amdgcn_sched_barrier(0);
  {
    const int orow = lane >> 3, og = lane & 7;
    const int lb = ((og ^ (orow & 7)) << 4);
    u16x8 o0 = *(const u16x8*)(pwb + orow * 128 + lb);
    u16x8 o1 = *(const u16x8*)(pwb + (8 + orow) * 128 + lb);
    *(u16x8*)(O + base + (size_t)(q0 + orow) * ND + og * 8) = o0;
    *(u16x8*)(O + base + (size_t)(q0 + 8 + orow) * ND + og * 8) = o1;
  }
}

// ---------------------------------------------------------------- launcher
extern "C" void kernel_launch(void* const* d_in, const int* in_sizes, int n_in,
                              void* d_out, int out_size, void* d_ws, size_t ws_size,
                              hipStream_t stream) {
  const float* x  = (const float*)d_in[0];
  const int*   tp = (const int*)d_in[1];
  const float* Wq = (const float*)d_in[2];
  const float* Wk = (const float*)d_in[3];
  const float* Wv = (const float*)d_in[4];
  const float* Wo = (const float*)d_in[5];
  float* out = (float*)d_out;

  const size_t MD2 = (size_t)NM * ND * 2;  // 16 MiB
  const size_t WW2 = (size_t)ND * ND * 2;  //  2 MiB
  char* w = (char*)d_ws;
  unsigned short* xb  = (unsigned short*)w; w += MD2;
  unsigned short* Qt  = (unsigned short*)w; w += MD2;   // Qt,Kt contiguous
  unsigned short* Kt  = (unsigned short*)w; w += MD2;
  unsigned short* Vt2 = (unsigned short*)w; w += MD2;
  unsigned short* Wqb = (unsigned short*)w; w += WW2;   // Wq,Wk,Wv contiguous
  unsigned short* Wkb = (unsigned short*)w; w += WW2;
  unsigned short* Wvb = (unsigned short*)w; w += WW2;
  unsigned short* Wob = (unsigned short*)w; w += WW2;
  unsigned short* Ot  = xb;  // alias: xb dead after gemm_qkv_fused

  cast_bf16<<<dim3(8192), 256, 0, stream>>>(x, xb, NM * ND / 4);
  cast_w4<<<dim3(1024, 4), 256, 0, stream>>>(Wq, Wk, Wv, Wo, Wqb, Wkb, Wvb, Wob);
  gemm_qkv_fused<<<dim3(16, 64), 256, 0, stream>>>(xb, Wqb, tp, Qt, Vt2);
  attn_kernel<<<dim3(1024), 512, 0, stream>>>(Qt, Kt, Vt2, Ot);
  gemm_out<<<dim3(8, 64), 256, 0, stream>>>(Ot, Wob, out);
}